// Round 5
// baseline (958.566 us; speedup 1.0000x reference)
//
#include <hip/hip_runtime.h>
#include <hip/hip_cooperative_groups.h>
#include <math.h>
#include <float.h>

namespace cg = cooperative_groups;

#define N_NODES 50000
#define N_EDGES 800000
#define D_INP   96
#define D_HID   128
#define N_B     512
#define SCAN_NB 98   // ceil(50000/512)

// ---------------------------------------------------------------------------
// Weight transposes + zero cnt (folded to save a memset dispatch)
__global__ void k_transpose(const float* __restrict__ W_in,
                            const float* __restrict__ W_ih,
                            const float* __restrict__ W_hh,
                            float* __restrict__ Wt_in,
                            float* __restrict__ Wt_g,
                            int* __restrict__ cnt) {
    int idx = blockIdx.x * 256 + threadIdx.x;
    if (idx < N_NODES) cnt[idx] = 0;
    if (idx < D_INP * D_HID) {
        int k = idx / D_HID, d = idx % D_HID;
        Wt_in[idx] = W_in[d * D_INP + k];
    }
    if (idx < 384 * 512) {
        int k = idx / 512, g = idx % 512;
        Wt_g[idx] = (k < 256) ? W_ih[g * 256 + k] : W_hh[g * 128 + (k - 256)];
    }
}

// ---------------------------------------------------------------------------
// In-degree count; also builds seg_ptr (folded, saves a dispatch)
__global__ void k_count(const int* __restrict__ dst, int* __restrict__ cnt,
                        const int* __restrict__ batch, int* __restrict__ seg_ptr) {
    int e = blockIdx.x * 256 + threadIdx.x;
    if (e < N_EDGES) atomicAdd(&cnt[dst[e]], 1);
    if (e < N_NODES) {
        int n = e;
        int bc = batch[n];
        int bp = (n == 0) ? -1 : batch[n - 1];
        for (int b = bp + 1; b <= bc; b++) seg_ptr[b] = n;
        if (n == N_NODES - 1)
            for (int b = bc + 1; b <= N_B; b++) seg_ptr[b] = N_NODES;
    }
}

__global__ __launch_bounds__(512) void k_scan_block(const int* __restrict__ cnt,
                                                    int* __restrict__ row_ptr,
                                                    int* __restrict__ partials,
                                                    float* __restrict__ deg_f) {
    __shared__ int sm[512];
    int i = blockIdx.x * 512 + threadIdx.x;
    int v = (i < N_NODES) ? cnt[i] : 0;
    sm[threadIdx.x] = v;
    __syncthreads();
    for (int off = 1; off < 512; off <<= 1) {
        int u = (threadIdx.x >= off) ? sm[threadIdx.x - off] : 0;
        __syncthreads();
        sm[threadIdx.x] += u;
        __syncthreads();
    }
    if (i < N_NODES) {
        row_ptr[i] = sm[threadIdx.x] - v;
        deg_f[i] = (float)max(v, 1);
    }
    if (threadIdx.x == 511) partials[blockIdx.x] = sm[511];
}

__global__ __launch_bounds__(128) void k_scan_part(int* __restrict__ partials,
                                                   int* __restrict__ row_ptr) {
    __shared__ int sm[128];
    int t = threadIdx.x;
    int v = (t < SCAN_NB) ? partials[t] : 0;
    sm[t] = v;
    __syncthreads();
    for (int off = 1; off < 128; off <<= 1) {
        int u = (t >= off) ? sm[t - off] : 0;
        __syncthreads();
        sm[t] += u;
        __syncthreads();
    }
    if (t < SCAN_NB) partials[t] = sm[t] - v;
    if (t == 127) row_ptr[N_NODES] = sm[127];
}

__global__ __launch_bounds__(512) void k_scan_add(int* __restrict__ row_ptr,
                                                  const int* __restrict__ partials,
                                                  int* __restrict__ cnt) {
    int i = blockIdx.x * 512 + threadIdx.x;
    if (i < N_NODES) {
        row_ptr[i] += partials[blockIdx.x];
        cnt[i] = 0;
    }
}

__global__ void k_scatter(const int* __restrict__ src, const int* __restrict__ dst,
                          const int* __restrict__ row_ptr, int* __restrict__ cnt,
                          int* __restrict__ esrc) {
    int e = blockIdx.x * 256 + threadIdx.x;
    if (e < N_EDGES) {
        int d = dst[e];
        int p = row_ptr[d] + atomicAdd(&cnt[d], 1);
        esrc[p] = src[e];
    }
}

// ---------------------------------------------------------------------------
// Input layer (row-major out). Also zero-inits the Set2Set state block.
__global__ __launch_bounds__(256) void k_ingemm(const float* __restrict__ x,
                                                const float* __restrict__ Wt_in,
                                                const float* __restrict__ b_in,
                                                float* __restrict__ h,
                                                float* __restrict__ zbase) {
    int gid = ((blockIdx.y * gridDim.x) + blockIdx.x) * 256 + threadIdx.x;
    if (gid < N_B * 512) zbase[gid] = 0.f;

    __shared__ __align__(16) float xs[64 * 96];
    __shared__ __align__(16) float ws[96 * 64];
    int n0 = blockIdx.x * 64;
    int d0 = blockIdx.y * 64;
    int tid = threadIdx.x;
    for (int j = tid; j < 64 * 96 / 4; j += 256) {
        int node = n0 + (j * 4) / 96;
        float4 v = make_float4(0.f, 0.f, 0.f, 0.f);
        if (node < N_NODES) v = *(const float4*)&x[n0 * 96 + j * 4];
        *(float4*)&xs[j * 4] = v;
    }
    for (int j = tid; j < 96 * 64 / 4; j += 256) {
        int k = (j * 4) / 64, dd = (j * 4) % 64;
        *(float4*)&ws[j * 4] = *(const float4*)&Wt_in[k * D_HID + d0 + dd];
    }
    __syncthreads();
    int tn = tid / 16;
    int td = tid % 16;
    float acc[4][4] = {};
    for (int k0 = 0; k0 < 96; k0 += 4) {
        float4 w0 = *(float4*)&ws[(k0 + 0) * 64 + td * 4];
        float4 w1 = *(float4*)&ws[(k0 + 1) * 64 + td * 4];
        float4 w2 = *(float4*)&ws[(k0 + 2) * 64 + td * 4];
        float4 w3 = *(float4*)&ws[(k0 + 3) * 64 + td * 4];
#pragma unroll
        for (int j = 0; j < 4; j++) {
            float4 xv = *(float4*)&xs[(tn * 4 + j) * 96 + k0];
            acc[j][0] += xv.x * w0.x + xv.y * w1.x + xv.z * w2.x + xv.w * w3.x;
            acc[j][1] += xv.x * w0.y + xv.y * w1.y + xv.z * w2.y + xv.w * w3.y;
            acc[j][2] += xv.x * w0.z + xv.y * w1.z + xv.z * w2.z + xv.w * w3.z;
            acc[j][3] += xv.x * w0.w + xv.y * w1.w + xv.z * w2.w + xv.w * w3.w;
        }
    }
    float4 bb = *(const float4*)&b_in[d0 + td * 4];
#pragma unroll
    for (int j = 0; j < 4; j++) {
        int node = n0 + tn * 4 + j;
        if (node < N_NODES) {
            float4 o;
            o.x = fmaxf(acc[j][0] + bb.x, 0.f);
            o.y = fmaxf(acc[j][1] + bb.y, 0.f);
            o.z = fmaxf(acc[j][2] + bb.z, 0.f);
            o.w = fmaxf(acc[j][3] + bb.w, 0.f);
            *(float4*)&h[(size_t)node * D_HID + d0 + td * 4] = o;
        }
    }
}

// ---------------------------------------------------------------------------
// MPNN step, row-major, unroll x8 + independent 4/2/1 remainder cascade:
// up to 8 outstanding 512B gathers per 32-lane group (latency hiding).
__global__ __launch_bounds__(256) void k_mpnn(const float* __restrict__ hin,
                                              float* __restrict__ hout,
                                              const int* __restrict__ row_ptr,
                                              const int* __restrict__ esrc,
                                              const float* __restrict__ deg_f) {
    int g = threadIdx.x >> 5;
    int l = threadIdx.x & 31;
    int n = blockIdx.x * 8 + g;
    if (n >= N_NODES) return;
    int s0 = row_ptr[n], s1 = row_ptr[n + 1];
    float4 a0{0,0,0,0}, a1{0,0,0,0}, a2{0,0,0,0}, a3{0,0,0,0};
    float4 a4{0,0,0,0}, a5{0,0,0,0}, a6{0,0,0,0}, a7{0,0,0,0};
    int i = s0;
    for (; i + 8 <= s1; i += 8) {
        int e0 = esrc[i + 0], e1 = esrc[i + 1], e2 = esrc[i + 2], e3 = esrc[i + 3];
        int e4 = esrc[i + 4], e5 = esrc[i + 5], e6 = esrc[i + 6], e7 = esrc[i + 7];
        float4 v0 = *(const float4*)&hin[(size_t)e0 * 128 + l * 4];
        float4 v1 = *(const float4*)&hin[(size_t)e1 * 128 + l * 4];
        float4 v2 = *(const float4*)&hin[(size_t)e2 * 128 + l * 4];
        float4 v3 = *(const float4*)&hin[(size_t)e3 * 128 + l * 4];
        float4 v4 = *(const float4*)&hin[(size_t)e4 * 128 + l * 4];
        float4 v5 = *(const float4*)&hin[(size_t)e5 * 128 + l * 4];
        float4 v6 = *(const float4*)&hin[(size_t)e6 * 128 + l * 4];
        float4 v7 = *(const float4*)&hin[(size_t)e7 * 128 + l * 4];
        a0.x += v0.x; a0.y += v0.y; a0.z += v0.z; a0.w += v0.w;
        a1.x += v1.x; a1.y += v1.y; a1.z += v1.z; a1.w += v1.w;
        a2.x += v2.x; a2.y += v2.y; a2.z += v2.z; a2.w += v2.w;
        a3.x += v3.x; a3.y += v3.y; a3.z += v3.z; a3.w += v3.w;
        a4.x += v4.x; a4.y += v4.y; a4.z += v4.z; a4.w += v4.w;
        a5.x += v5.x; a5.y += v5.y; a5.z += v5.z; a5.w += v5.w;
        a6.x += v6.x; a6.y += v6.y; a6.z += v6.z; a6.w += v6.w;
        a7.x += v7.x; a7.y += v7.y; a7.z += v7.z; a7.w += v7.w;
    }
    if (i + 4 <= s1) {
        int e0 = esrc[i + 0], e1 = esrc[i + 1], e2 = esrc[i + 2], e3 = esrc[i + 3];
        float4 v0 = *(const float4*)&hin[(size_t)e0 * 128 + l * 4];
        float4 v1 = *(const float4*)&hin[(size_t)e1 * 128 + l * 4];
        float4 v2 = *(const float4*)&hin[(size_t)e2 * 128 + l * 4];
        float4 v3 = *(const float4*)&hin[(size_t)e3 * 128 + l * 4];
        a0.x += v0.x; a0.y += v0.y; a0.z += v0.z; a0.w += v0.w;
        a1.x += v1.x; a1.y += v1.y; a1.z += v1.z; a1.w += v1.w;
        a2.x += v2.x; a2.y += v2.y; a2.z += v2.z; a2.w += v2.w;
        a3.x += v3.x; a3.y += v3.y; a3.z += v3.z; a3.w += v3.w;
        i += 4;
    }
    if (i + 2 <= s1) {
        int e0 = esrc[i + 0], e1 = esrc[i + 1];
        float4 v0 = *(const float4*)&hin[(size_t)e0 * 128 + l * 4];
        float4 v1 = *(const float4*)&hin[(size_t)e1 * 128 + l * 4];
        a4.x += v0.x; a4.y += v0.y; a4.z += v0.z; a4.w += v0.w;
        a5.x += v1.x; a5.y += v1.y; a5.z += v1.z; a5.w += v1.w;
        i += 2;
    }
    if (i < s1) {
        int e0 = esrc[i];
        float4 v0 = *(const float4*)&hin[(size_t)e0 * 128 + l * 4];
        a6.x += v0.x; a6.y += v0.y; a6.z += v0.z; a6.w += v0.w;
    }
    a0.x += a1.x + a2.x + a3.x + a4.x + a5.x + a6.x + a7.x;
    a0.y += a1.y + a2.y + a3.y + a4.y + a5.y + a6.y + a7.y;
    a0.z += a1.z + a2.z + a3.z + a4.z + a5.z + a6.z + a7.z;
    a0.w += a1.w + a2.w + a3.w + a4.w + a5.w + a6.w + a7.w;
    float invd = 1.0f / deg_f[n];
    float4 hv = *(const float4*)&hin[(size_t)n * 128 + l * 4];
    float4 o;
    o.x = (hv.x + a0.x * invd) * 0.5f;
    o.y = (hv.y + a0.y * invd) * 0.5f;
    o.z = (hv.z + a0.z * invd) * 0.5f;
    o.w = (hv.w + a0.w * invd) * 0.5f;
    *(float4*)&hout[(size_t)n * 128 + l * 4] = o;
}

__device__ __forceinline__ float sigmoidf_(float v) { return 1.0f / (1.0f + expf(-v)); }

// ---------------------------------------------------------------------------
// Fully fused Set2Set: 3 x (gates GEMM + LSTM | grid.sync | attention),
// last attention also computes the prediction head. Cooperative launch,
// 512 blocks x 128 threads (co-resident: 1024 waves << 8192 capacity).
__global__ __launch_bounds__(128) void k_s2s(
        float* __restrict__ qstar, float* __restrict__ hh, float* __restrict__ cc,
        const float* __restrict__ Wt_g, const float* __restrict__ b_ih,
        const float* __restrict__ b_hh, const float* __restrict__ h,
        const int* __restrict__ seg_ptr, const float* __restrict__ W_pred,
        const float* __restrict__ b_pred, float* __restrict__ out) {
    cg::grid_group grid = cg::this_grid();
    __shared__ __align__(16) float als[4 * 384];
    __shared__ __align__(16) float gls[4 * 512];
    __shared__ float smax[4];
    __shared__ float ssum[4];
    __shared__ __align__(16) float sr[4][128];
    int tid = threadIdx.x;

    for (int step = 0; step < 3; step++) {
        // ---- phase 1: gates GEMM + LSTM (blocks 0..127, 4 batch rows each)
        if (blockIdx.x < 128) {
            int b0 = blockIdx.x * 4;
            for (int i = tid; i < 4 * 384; i += 128) {
                int bb = i / 384, k = i % 384;
                als[i] = (k < 256) ? qstar[(b0 + bb) * 256 + k]
                                   : hh[(b0 + bb) * 128 + (k - 256)];
            }
            __syncthreads();
            int gg = tid * 4;
            float4 acc[4] = {};
            for (int k = 0; k < 384; k++) {
                float4 w = *(const float4*)&Wt_g[k * 512 + gg];
#pragma unroll
                for (int r = 0; r < 4; r++) {
                    float a = als[r * 384 + k];
                    acc[r].x += a * w.x; acc[r].y += a * w.y;
                    acc[r].z += a * w.z; acc[r].w += a * w.w;
                }
            }
            float4 bias;
            bias.x = b_ih[gg + 0] + b_hh[gg + 0];
            bias.y = b_ih[gg + 1] + b_hh[gg + 1];
            bias.z = b_ih[gg + 2] + b_hh[gg + 2];
            bias.w = b_ih[gg + 3] + b_hh[gg + 3];
#pragma unroll
            for (int r = 0; r < 4; r++) {
                float4 o;
                o.x = acc[r].x + bias.x; o.y = acc[r].y + bias.y;
                o.z = acc[r].z + bias.z; o.w = acc[r].w + bias.w;
                *(float4*)&gls[r * 512 + gg] = o;
            }
            __syncthreads();
            int dd = tid;
#pragma unroll
            for (int r = 0; r < 4; r++) {
                int b = b0 + r;
                float ig = gls[r * 512 + dd];
                float fg = gls[r * 512 + 128 + dd];
                float gv = gls[r * 512 + 256 + dd];
                float og = gls[r * 512 + 384 + dd];
                float c = sigmoidf_(fg) * cc[b * 128 + dd] + sigmoidf_(ig) * tanhf(gv);
                cc[b * 128 + dd] = c;
                float hv = sigmoidf_(og) * tanhf(c);
                hh[b * 128 + dd] = hv;
                qstar[b * 256 + dd] = hv;
            }
            __threadfence();
        }
        grid.sync();

        // ---- phase 2: online-softmax attention (all 512 blocks, 1 graph each)
        {
            int b = blockIdx.x;
            int g = tid >> 5, l = tid & 31;
            int s0 = seg_ptr[b], s1 = seg_ptr[b + 1];
            float4 q = *(const float4*)&hh[b * 128 + l * 4];
            float M = -INFINITY, asum = 0.f;
            float4 racc = make_float4(0.f, 0.f, 0.f, 0.f);
            for (int n = s0 + g; n < s1; n += 4) {
                float4 hv = *(const float4*)&h[(size_t)n * 128 + l * 4];
                float d = hv.x * q.x + hv.y * q.y + hv.z * q.z + hv.w * q.w;
                for (int m = 16; m >= 1; m >>= 1) d += __shfl_xor(d, m, 64);
                float newM = fmaxf(M, d);
                float scale = expf(M - newM);
                float a = expf(d - newM);
                asum = asum * scale + a;
                racc.x = racc.x * scale + a * hv.x;
                racc.y = racc.y * scale + a * hv.y;
                racc.z = racc.z * scale + a * hv.z;
                racc.w = racc.w * scale + a * hv.w;
                M = newM;
            }
            __syncthreads();   // reuse of shared between steps
            if (l == 0) { smax[g] = M; ssum[g] = asum; }
            *(float4*)&sr[g][l * 4] = racc;
            __syncthreads();
            if (g == 0) {
                float Mx = fmaxf(fmaxf(smax[0], smax[1]), fmaxf(smax[2], smax[3]));
                float4 o = make_float4(0.f, 0.f, 0.f, 0.f);
                if (Mx > -INFINITY) {
                    float w0 = expf(smax[0] - Mx), w1 = expf(smax[1] - Mx);
                    float w2 = expf(smax[2] - Mx), w3 = expf(smax[3] - Mx);
                    float tot = ssum[0] * w0 + ssum[1] * w1 + ssum[2] * w2 + ssum[3] * w3;
                    float inv = 1.0f / (tot + 1e-16f);
                    float4 r0 = *(float4*)&sr[0][l * 4];
                    float4 r1 = *(float4*)&sr[1][l * 4];
                    float4 r2 = *(float4*)&sr[2][l * 4];
                    float4 r3 = *(float4*)&sr[3][l * 4];
                    o.x = (r0.x * w0 + r1.x * w1 + r2.x * w2 + r3.x * w3) * inv;
                    o.y = (r0.y * w0 + r1.y * w1 + r2.y * w2 + r3.y * w3) * inv;
                    o.z = (r0.z * w0 + r1.z * w1 + r2.z * w2 + r3.z * w3) * inv;
                    o.w = (r0.w * w0 + r1.w * w1 + r2.w * w2 + r3.w * w3) * inv;
                }
                *(float4*)&qstar[b * 256 + 128 + l * 4] = o;
                if (step == 2) {
                    float4 wq = *(const float4*)&W_pred[l * 4];
                    float4 wr = *(const float4*)&W_pred[128 + l * 4];
                    float d = q.x * wq.x + q.y * wq.y + q.z * wq.z + q.w * wq.w
                            + o.x * wr.x + o.y * wr.y + o.z * wr.z + o.w * wr.w;
                    for (int m = 16; m >= 1; m >>= 1) d += __shfl_xor(d, m, 64);
                    if (l == 0) out[b] = d + b_pred[0];
                }
            }
            if (step < 2) {
                __threadfence();
                grid.sync();
            }
        }
    }
}

// ---------------------------------------------------------------------------
extern "C" void kernel_launch(void* const* d_in, const int* in_sizes, int n_in,
                              void* d_out, int out_size, void* d_ws, size_t ws_size,
                              hipStream_t stream) {
    const float* x      = (const float*)d_in[0];
    const int*   edge   = (const int*)d_in[1];
    const int*   batch  = (const int*)d_in[2];
    const float* W_in   = (const float*)d_in[3];
    const float* b_in   = (const float*)d_in[4];
    const float* W_ih   = (const float*)d_in[5];
    const float* W_hh   = (const float*)d_in[6];
    const float* b_ih   = (const float*)d_in[7];
    const float* b_hh   = (const float*)d_in[8];
    const float* W_pred = (const float*)d_in[9];
    const float* b_pred = (const float*)d_in[10];
    float* out = (float*)d_out;

    const int* src = edge;
    const int* dst = edge + N_EDGES;

    float* f = (float*)d_ws;
    float* h0    = f;                     f += (size_t)N_NODES * D_HID;
    float* h1    = f;                     f += (size_t)N_NODES * D_HID;
    float* deg_f = f;                     f += N_NODES;
    float* qstar = f;                     f += (size_t)N_B * 256;   // qstar|hh|cc contiguous
    float* hh    = f;                     f += (size_t)N_B * 128;
    float* cc    = f;                     f += (size_t)N_B * 128;
    float* Wt_in = f;                     f += D_INP * D_HID;
    float* Wt_g  = f;                     f += 384 * 512;
    int* ip = (int*)f;
    int* row_ptr = ip;                    ip += N_NODES + 1;
    int* cnt     = ip;                    ip += N_NODES;
    int* esrc    = ip;                    ip += N_EDGES;
    int* seg_ptr = ip;                    ip += N_B + 1;
    int* partials = ip;                   ip += 128;

    // ---- CSR build + seg_ptr + weight transposes
    k_transpose<<<768, 256, 0, stream>>>(W_in, W_ih, W_hh, Wt_in, Wt_g, cnt);
    k_count<<<(N_EDGES + 255) / 256, 256, 0, stream>>>(dst, cnt, batch, seg_ptr);
    k_scan_block<<<SCAN_NB, 512, 0, stream>>>(cnt, row_ptr, partials, deg_f);
    k_scan_part<<<1, 128, 0, stream>>>(partials, row_ptr);
    k_scan_add<<<SCAN_NB, 512, 0, stream>>>(row_ptr, partials, cnt);  // re-zeroes cnt
    k_scatter<<<(N_EDGES + 255) / 256, 256, 0, stream>>>(src, dst, row_ptr, cnt, esrc);

    // ---- input layer (also zero-inits qstar|hh|cc)
    k_ingemm<<<dim3((N_NODES + 63) / 64, 2), 256, 0, stream>>>(x, Wt_in, b_in, h0, qstar);

    // ---- 4 MPNN steps (ping-pong, ends in h0)
    int mb = (N_NODES + 7) / 8;
    k_mpnn<<<mb, 256, 0, stream>>>(h0, h1, row_ptr, esrc, deg_f);
    k_mpnn<<<mb, 256, 0, stream>>>(h1, h0, row_ptr, esrc, deg_f);
    k_mpnn<<<mb, 256, 0, stream>>>(h0, h1, row_ptr, esrc, deg_f);
    k_mpnn<<<mb, 256, 0, stream>>>(h1, h0, row_ptr, esrc, deg_f);

    // ---- fused Set2Set + head (cooperative: grid-wide syncs inside)
    void* args[] = {&qstar, &hh, &cc, &Wt_g, &b_ih, &b_hh, &h0, &seg_ptr,
                    &W_pred, &b_pred, &out};
    hipLaunchCooperativeKernel((void*)k_s2s, dim3(N_B), dim3(128), args, 0, stream);
}

// Round 6
// 583.284 us; speedup vs baseline: 1.6434x; 1.6434x over previous
//
#include <hip/hip_runtime.h>
#include <math.h>
#include <float.h>

#define N_NODES 50000
#define N_EDGES 800000
#define D_INP   96
#define D_HID   128
#define N_B     512
#define SCAN_NB 98   // ceil(50000/512)

// ---------------------------------------------------------------------------
// Weight transposes + zero cnt (folded to save a memset dispatch)
__global__ void k_transpose(const float* __restrict__ W_in,
                            const float* __restrict__ W_ih,
                            const float* __restrict__ W_hh,
                            float* __restrict__ Wt_in,
                            float* __restrict__ Wt_g,
                            int* __restrict__ cnt) {
    int idx = blockIdx.x * 256 + threadIdx.x;
    if (idx < N_NODES) cnt[idx] = 0;
    if (idx < D_INP * D_HID) {
        int k = idx / D_HID, d = idx % D_HID;
        Wt_in[idx] = W_in[d * D_INP + k];
    }
    if (idx < 384 * 512) {
        int k = idx / 512, g = idx % 512;
        Wt_g[idx] = (k < 256) ? W_ih[g * 256 + k] : W_hh[g * 128 + (k - 256)];
    }
}

// ---------------------------------------------------------------------------
// In-degree count; also builds seg_ptr (folded, saves a dispatch)
__global__ void k_count(const int* __restrict__ dst, int* __restrict__ cnt,
                        const int* __restrict__ batch, int* __restrict__ seg_ptr) {
    int e = blockIdx.x * 256 + threadIdx.x;
    if (e < N_EDGES) atomicAdd(&cnt[dst[e]], 1);
    if (e < N_NODES) {
        int n = e;
        int bc = batch[n];
        int bp = (n == 0) ? -1 : batch[n - 1];
        for (int b = bp + 1; b <= bc; b++) seg_ptr[b] = n;
        if (n == N_NODES - 1)
            for (int b = bc + 1; b <= N_B; b++) seg_ptr[b] = N_NODES;
    }
}

__global__ __launch_bounds__(512) void k_scan_block(const int* __restrict__ cnt,
                                                    int* __restrict__ row_ptr,
                                                    int* __restrict__ partials,
                                                    float* __restrict__ deg_f) {
    __shared__ int sm[512];
    int i = blockIdx.x * 512 + threadIdx.x;
    int v = (i < N_NODES) ? cnt[i] : 0;
    sm[threadIdx.x] = v;
    __syncthreads();
    for (int off = 1; off < 512; off <<= 1) {
        int u = (threadIdx.x >= off) ? sm[threadIdx.x - off] : 0;
        __syncthreads();
        sm[threadIdx.x] += u;
        __syncthreads();
    }
    if (i < N_NODES) {
        row_ptr[i] = sm[threadIdx.x] - v;
        deg_f[i] = (float)max(v, 1);
    }
    if (threadIdx.x == 511) partials[blockIdx.x] = sm[511];
}

__global__ __launch_bounds__(128) void k_scan_part(int* __restrict__ partials,
                                                   int* __restrict__ row_ptr) {
    __shared__ int sm[128];
    int t = threadIdx.x;
    int v = (t < SCAN_NB) ? partials[t] : 0;
    sm[t] = v;
    __syncthreads();
    for (int off = 1; off < 128; off <<= 1) {
        int u = (t >= off) ? sm[t - off] : 0;
        __syncthreads();
        sm[t] += u;
        __syncthreads();
    }
    if (t < SCAN_NB) partials[t] = sm[t] - v;
    if (t == 127) row_ptr[N_NODES] = sm[127];
}

__global__ __launch_bounds__(512) void k_scan_add(int* __restrict__ row_ptr,
                                                  const int* __restrict__ partials,
                                                  int* __restrict__ cnt) {
    int i = blockIdx.x * 512 + threadIdx.x;
    if (i < N_NODES) {
        row_ptr[i] += partials[blockIdx.x];
        cnt[i] = 0;
    }
}

__global__ void k_scatter(const int* __restrict__ src, const int* __restrict__ dst,
                          const int* __restrict__ row_ptr, int* __restrict__ cnt,
                          int* __restrict__ esrc) {
    int e = blockIdx.x * 256 + threadIdx.x;
    if (e < N_EDGES) {
        int d = dst[e];
        int p = row_ptr[d] + atomicAdd(&cnt[d], 1);
        esrc[p] = src[e];
    }
}

// ---------------------------------------------------------------------------
// Input layer (row-major out). Also zero-inits the Set2Set state block.
__global__ __launch_bounds__(256) void k_ingemm(const float* __restrict__ x,
                                                const float* __restrict__ Wt_in,
                                                const float* __restrict__ b_in,
                                                float* __restrict__ h,
                                                float* __restrict__ zbase) {
    int gid = ((blockIdx.y * gridDim.x) + blockIdx.x) * 256 + threadIdx.x;
    if (gid < N_B * 512) zbase[gid] = 0.f;

    __shared__ __align__(16) float xs[64 * 96];
    __shared__ __align__(16) float ws[96 * 64];
    int n0 = blockIdx.x * 64;
    int d0 = blockIdx.y * 64;
    int tid = threadIdx.x;
    for (int j = tid; j < 64 * 96 / 4; j += 256) {
        int node = n0 + (j * 4) / 96;
        float4 v = make_float4(0.f, 0.f, 0.f, 0.f);
        if (node < N_NODES) v = *(const float4*)&x[n0 * 96 + j * 4];
        *(float4*)&xs[j * 4] = v;
    }
    for (int j = tid; j < 96 * 64 / 4; j += 256) {
        int k = (j * 4) / 64, dd = (j * 4) % 64;
        *(float4*)&ws[j * 4] = *(const float4*)&Wt_in[k * D_HID + d0 + dd];
    }
    __syncthreads();
    int tn = tid / 16;
    int td = tid % 16;
    float acc[4][4] = {};
    for (int k0 = 0; k0 < 96; k0 += 4) {
        float4 w0 = *(float4*)&ws[(k0 + 0) * 64 + td * 4];
        float4 w1 = *(float4*)&ws[(k0 + 1) * 64 + td * 4];
        float4 w2 = *(float4*)&ws[(k0 + 2) * 64 + td * 4];
        float4 w3 = *(float4*)&ws[(k0 + 3) * 64 + td * 4];
#pragma unroll
        for (int j = 0; j < 4; j++) {
            float4 xv = *(float4*)&xs[(tn * 4 + j) * 96 + k0];
            acc[j][0] += xv.x * w0.x + xv.y * w1.x + xv.z * w2.x + xv.w * w3.x;
            acc[j][1] += xv.x * w0.y + xv.y * w1.y + xv.z * w2.y + xv.w * w3.y;
            acc[j][2] += xv.x * w0.z + xv.y * w1.z + xv.z * w2.z + xv.w * w3.z;
            acc[j][3] += xv.x * w0.w + xv.y * w1.w + xv.z * w2.w + xv.w * w3.w;
        }
    }
    float4 bb = *(const float4*)&b_in[d0 + td * 4];
#pragma unroll
    for (int j = 0; j < 4; j++) {
        int node = n0 + tn * 4 + j;
        if (node < N_NODES) {
            float4 o;
            o.x = fmaxf(acc[j][0] + bb.x, 0.f);
            o.y = fmaxf(acc[j][1] + bb.y, 0.f);
            o.z = fmaxf(acc[j][2] + bb.z, 0.f);
            o.w = fmaxf(acc[j][3] + bb.w, 0.f);
            *(float4*)&h[(size_t)node * D_HID + d0 + td * 4] = o;
        }
    }
}

// ---------------------------------------------------------------------------
// MPNN step, row-major, unroll x8 + independent 4/2/1 remainder cascade:
// up to 8 outstanding 512B gathers per 32-lane group (latency hiding).
__global__ __launch_bounds__(256) void k_mpnn(const float* __restrict__ hin,
                                              float* __restrict__ hout,
                                              const int* __restrict__ row_ptr,
                                              const int* __restrict__ esrc,
                                              const float* __restrict__ deg_f) {
    int g = threadIdx.x >> 5;
    int l = threadIdx.x & 31;
    int n = blockIdx.x * 8 + g;
    if (n >= N_NODES) return;
    int s0 = row_ptr[n], s1 = row_ptr[n + 1];
    float4 a0{0,0,0,0}, a1{0,0,0,0}, a2{0,0,0,0}, a3{0,0,0,0};
    float4 a4{0,0,0,0}, a5{0,0,0,0}, a6{0,0,0,0}, a7{0,0,0,0};
    int i = s0;
    for (; i + 8 <= s1; i += 8) {
        int e0 = esrc[i + 0], e1 = esrc[i + 1], e2 = esrc[i + 2], e3 = esrc[i + 3];
        int e4 = esrc[i + 4], e5 = esrc[i + 5], e6 = esrc[i + 6], e7 = esrc[i + 7];
        float4 v0 = *(const float4*)&hin[(size_t)e0 * 128 + l * 4];
        float4 v1 = *(const float4*)&hin[(size_t)e1 * 128 + l * 4];
        float4 v2 = *(const float4*)&hin[(size_t)e2 * 128 + l * 4];
        float4 v3 = *(const float4*)&hin[(size_t)e3 * 128 + l * 4];
        float4 v4 = *(const float4*)&hin[(size_t)e4 * 128 + l * 4];
        float4 v5 = *(const float4*)&hin[(size_t)e5 * 128 + l * 4];
        float4 v6 = *(const float4*)&hin[(size_t)e6 * 128 + l * 4];
        float4 v7 = *(const float4*)&hin[(size_t)e7 * 128 + l * 4];
        a0.x += v0.x; a0.y += v0.y; a0.z += v0.z; a0.w += v0.w;
        a1.x += v1.x; a1.y += v1.y; a1.z += v1.z; a1.w += v1.w;
        a2.x += v2.x; a2.y += v2.y; a2.z += v2.z; a2.w += v2.w;
        a3.x += v3.x; a3.y += v3.y; a3.z += v3.z; a3.w += v3.w;
        a4.x += v4.x; a4.y += v4.y; a4.z += v4.z; a4.w += v4.w;
        a5.x += v5.x; a5.y += v5.y; a5.z += v5.z; a5.w += v5.w;
        a6.x += v6.x; a6.y += v6.y; a6.z += v6.z; a6.w += v6.w;
        a7.x += v7.x; a7.y += v7.y; a7.z += v7.z; a7.w += v7.w;
    }
    if (i + 4 <= s1) {
        int e0 = esrc[i + 0], e1 = esrc[i + 1], e2 = esrc[i + 2], e3 = esrc[i + 3];
        float4 v0 = *(const float4*)&hin[(size_t)e0 * 128 + l * 4];
        float4 v1 = *(const float4*)&hin[(size_t)e1 * 128 + l * 4];
        float4 v2 = *(const float4*)&hin[(size_t)e2 * 128 + l * 4];
        float4 v3 = *(const float4*)&hin[(size_t)e3 * 128 + l * 4];
        a0.x += v0.x; a0.y += v0.y; a0.z += v0.z; a0.w += v0.w;
        a1.x += v1.x; a1.y += v1.y; a1.z += v1.z; a1.w += v1.w;
        a2.x += v2.x; a2.y += v2.y; a2.z += v2.z; a2.w += v2.w;
        a3.x += v3.x; a3.y += v3.y; a3.z += v3.z; a3.w += v3.w;
        i += 4;
    }
    if (i + 2 <= s1) {
        int e0 = esrc[i + 0], e1 = esrc[i + 1];
        float4 v0 = *(const float4*)&hin[(size_t)e0 * 128 + l * 4];
        float4 v1 = *(const float4*)&hin[(size_t)e1 * 128 + l * 4];
        a4.x += v0.x; a4.y += v0.y; a4.z += v0.z; a4.w += v0.w;
        a5.x += v1.x; a5.y += v1.y; a5.z += v1.z; a5.w += v1.w;
        i += 2;
    }
    if (i < s1) {
        int e0 = esrc[i];
        float4 v0 = *(const float4*)&hin[(size_t)e0 * 128 + l * 4];
        a6.x += v0.x; a6.y += v0.y; a6.z += v0.z; a6.w += v0.w;
    }
    a0.x += a1.x + a2.x + a3.x + a4.x + a5.x + a6.x + a7.x;
    a0.y += a1.y + a2.y + a3.y + a4.y + a5.y + a6.y + a7.y;
    a0.z += a1.z + a2.z + a3.z + a4.z + a5.z + a6.z + a7.z;
    a0.w += a1.w + a2.w + a3.w + a4.w + a5.w + a6.w + a7.w;
    float invd = 1.0f / deg_f[n];
    float4 hv = *(const float4*)&hin[(size_t)n * 128 + l * 4];
    float4 o;
    o.x = (hv.x + a0.x * invd) * 0.5f;
    o.y = (hv.y + a0.y * invd) * 0.5f;
    o.z = (hv.z + a0.z * invd) * 0.5f;
    o.w = (hv.w + a0.w * invd) * 0.5f;
    *(float4*)&hout[(size_t)n * 128 + l * 4] = o;
}

__device__ __forceinline__ float sigmoidf_(float v) { return 1.0f / (1.0f + expf(-v)); }

// ---------------------------------------------------------------------------
// Fused gates GEMM + LSTM. One block handles 4 batch rows, all 512 gates.
__global__ __launch_bounds__(128) void k_gates_lstm(float* __restrict__ qstar,
                                                    float* __restrict__ hh,
                                                    float* __restrict__ cc,
                                                    const float* __restrict__ Wt_g,
                                                    const float* __restrict__ b_ih,
                                                    const float* __restrict__ b_hh) {
    __shared__ __align__(16) float als[4 * 384];
    __shared__ __align__(16) float gls[4 * 512];
    int b0 = blockIdx.x * 4;
    int tid = threadIdx.x;
    for (int i = tid; i < 4 * 384; i += 128) {
        int bb = i / 384, k = i % 384;
        als[i] = (k < 256) ? qstar[(b0 + bb) * 256 + k]
                           : hh[(b0 + bb) * 128 + (k - 256)];
    }
    __syncthreads();
    int g = tid * 4;
    float4 acc[4] = {};
    for (int k = 0; k < 384; k++) {
        float4 w = *(const float4*)&Wt_g[k * 512 + g];
#pragma unroll
        for (int r = 0; r < 4; r++) {
            float a = als[r * 384 + k];
            acc[r].x += a * w.x; acc[r].y += a * w.y;
            acc[r].z += a * w.z; acc[r].w += a * w.w;
        }
    }
    float4 bias;
    bias.x = b_ih[g + 0] + b_hh[g + 0];
    bias.y = b_ih[g + 1] + b_hh[g + 1];
    bias.z = b_ih[g + 2] + b_hh[g + 2];
    bias.w = b_ih[g + 3] + b_hh[g + 3];
#pragma unroll
    for (int r = 0; r < 4; r++) {
        float4 o;
        o.x = acc[r].x + bias.x; o.y = acc[r].y + bias.y;
        o.z = acc[r].z + bias.z; o.w = acc[r].w + bias.w;
        *(float4*)&gls[r * 512 + g] = o;
    }
    __syncthreads();
    int dd = tid;
#pragma unroll
    for (int r = 0; r < 4; r++) {
        int b = b0 + r;
        float ig = gls[r * 512 + dd];
        float fg = gls[r * 512 + 128 + dd];
        float gg = gls[r * 512 + 256 + dd];
        float og = gls[r * 512 + 384 + dd];
        float c = sigmoidf_(fg) * cc[b * 128 + dd] + sigmoidf_(ig) * tanhf(gg);
        cc[b * 128 + dd] = c;
        float hv = sigmoidf_(og) * tanhf(c);
        hh[b * 128 + dd] = hv;
        qstar[b * 256 + dd] = hv;
    }
}

// ---------------------------------------------------------------------------
// Online-softmax segment attention; when LAST, also computes the head.
template <bool LAST>
__global__ __launch_bounds__(128) void k_attn(const float* __restrict__ h,
                                              const float* __restrict__ hh,
                                              const int* __restrict__ seg_ptr,
                                              float* __restrict__ qstar,
                                              const float* __restrict__ W_pred,
                                              const float* __restrict__ b_pred,
                                              float* __restrict__ out) {
    int b = blockIdx.x;
    int g = threadIdx.x >> 5, l = threadIdx.x & 31;
    int s0 = seg_ptr[b], s1 = seg_ptr[b + 1];
    float4 q = *(const float4*)&hh[b * 128 + l * 4];
    float M = -INFINITY, asum = 0.f;
    float4 racc = make_float4(0.f, 0.f, 0.f, 0.f);
    for (int n = s0 + g; n < s1; n += 4) {
        float4 hv = *(const float4*)&h[(size_t)n * 128 + l * 4];
        float d = hv.x * q.x + hv.y * q.y + hv.z * q.z + hv.w * q.w;
        for (int m = 16; m >= 1; m >>= 1) d += __shfl_xor(d, m, 64);
        float newM = fmaxf(M, d);
        float scale = expf(M - newM);
        float a = expf(d - newM);
        asum = asum * scale + a;
        racc.x = racc.x * scale + a * hv.x;
        racc.y = racc.y * scale + a * hv.y;
        racc.z = racc.z * scale + a * hv.z;
        racc.w = racc.w * scale + a * hv.w;
        M = newM;
    }
    __shared__ float smax[4];
    __shared__ float ssum[4];
    __shared__ __align__(16) float sr[4][128];
    if (l == 0) { smax[g] = M; ssum[g] = asum; }
    *(float4*)&sr[g][l * 4] = racc;
    __syncthreads();
    if (g == 0) {
        float Mx = fmaxf(fmaxf(smax[0], smax[1]), fmaxf(smax[2], smax[3]));
        float4 o = make_float4(0.f, 0.f, 0.f, 0.f);
        if (Mx > -INFINITY) {
            float w0 = expf(smax[0] - Mx), w1 = expf(smax[1] - Mx);
            float w2 = expf(smax[2] - Mx), w3 = expf(smax[3] - Mx);
            float tot = ssum[0] * w0 + ssum[1] * w1 + ssum[2] * w2 + ssum[3] * w3;
            float inv = 1.0f / (tot + 1e-16f);
            float4 r0 = *(float4*)&sr[0][l * 4];
            float4 r1 = *(float4*)&sr[1][l * 4];
            float4 r2 = *(float4*)&sr[2][l * 4];
            float4 r3 = *(float4*)&sr[3][l * 4];
            o.x = (r0.x * w0 + r1.x * w1 + r2.x * w2 + r3.x * w3) * inv;
            o.y = (r0.y * w0 + r1.y * w1 + r2.y * w2 + r3.y * w3) * inv;
            o.z = (r0.z * w0 + r1.z * w1 + r2.z * w2 + r3.z * w3) * inv;
            o.w = (r0.w * w0 + r1.w * w1 + r2.w * w2 + r3.w * w3) * inv;
        }
        *(float4*)&qstar[b * 256 + 128 + l * 4] = o;
        if (LAST) {
            float4 wq = *(const float4*)&W_pred[l * 4];
            float4 wr = *(const float4*)&W_pred[128 + l * 4];
            float d = q.x * wq.x + q.y * wq.y + q.z * wq.z + q.w * wq.w
                    + o.x * wr.x + o.y * wr.y + o.z * wr.z + o.w * wr.w;
            for (int m = 16; m >= 1; m >>= 1) d += __shfl_xor(d, m, 64);
            if (l == 0) out[b] = d + b_pred[0];
        }
    }
}

// ---------------------------------------------------------------------------
extern "C" void kernel_launch(void* const* d_in, const int* in_sizes, int n_in,
                              void* d_out, int out_size, void* d_ws, size_t ws_size,
                              hipStream_t stream) {
    const float* x      = (const float*)d_in[0];
    const int*   edge   = (const int*)d_in[1];
    const int*   batch  = (const int*)d_in[2];
    const float* W_in   = (const float*)d_in[3];
    const float* b_in   = (const float*)d_in[4];
    const float* W_ih   = (const float*)d_in[5];
    const float* W_hh   = (const float*)d_in[6];
    const float* b_ih   = (const float*)d_in[7];
    const float* b_hh   = (const float*)d_in[8];
    const float* W_pred = (const float*)d_in[9];
    const float* b_pred = (const float*)d_in[10];
    float* out = (float*)d_out;

    const int* src = edge;
    const int* dst = edge + N_EDGES;

    float* f = (float*)d_ws;
    float* h0    = f;                     f += (size_t)N_NODES * D_HID;
    float* h1    = f;                     f += (size_t)N_NODES * D_HID;
    float* deg_f = f;                     f += N_NODES;
    float* qstar = f;                     f += (size_t)N_B * 256;   // qstar|hh|cc contiguous
    float* hh    = f;                     f += (size_t)N_B * 128;
    float* cc    = f;                     f += (size_t)N_B * 128;
    float* Wt_in = f;                     f += D_INP * D_HID;
    float* Wt_g  = f;                     f += 384 * 512;
    int* ip = (int*)f;
    int* row_ptr = ip;                    ip += N_NODES + 1;
    int* cnt     = ip;                    ip += N_NODES;
    int* esrc    = ip;                    ip += N_EDGES;
    int* seg_ptr = ip;                    ip += N_B + 1;
    int* partials = ip;                   ip += 128;

    // ---- CSR build + seg_ptr + weight transposes
    k_transpose<<<768, 256, 0, stream>>>(W_in, W_ih, W_hh, Wt_in, Wt_g, cnt);
    k_count<<<(N_EDGES + 255) / 256, 256, 0, stream>>>(dst, cnt, batch, seg_ptr);
    k_scan_block<<<SCAN_NB, 512, 0, stream>>>(cnt, row_ptr, partials, deg_f);
    k_scan_part<<<1, 128, 0, stream>>>(partials, row_ptr);
    k_scan_add<<<SCAN_NB, 512, 0, stream>>>(row_ptr, partials, cnt);  // re-zeroes cnt
    k_scatter<<<(N_EDGES + 255) / 256, 256, 0, stream>>>(src, dst, row_ptr, cnt, esrc);

    // ---- input layer (also zero-inits qstar|hh|cc)
    k_ingemm<<<dim3((N_NODES + 63) / 64, 2), 256, 0, stream>>>(x, Wt_in, b_in, h0, qstar);

    // ---- 4 MPNN steps (ping-pong, ends in h0)
    int mb = (N_NODES + 7) / 8;
    k_mpnn<<<mb, 256, 0, stream>>>(h0, h1, row_ptr, esrc, deg_f);
    k_mpnn<<<mb, 256, 0, stream>>>(h1, h0, row_ptr, esrc, deg_f);
    k_mpnn<<<mb, 256, 0, stream>>>(h0, h1, row_ptr, esrc, deg_f);
    k_mpnn<<<mb, 256, 0, stream>>>(h1, h0, row_ptr, esrc, deg_f);

    // ---- Set2Set: (gates+lstm) fused, attn (last one also does the head)
    for (int step = 0; step < 3; step++) {
        k_gates_lstm<<<N_B / 4, 128, 0, stream>>>(qstar, hh, cc, Wt_g, b_ih, b_hh);
        if (step < 2)
            k_attn<false><<<N_B, 128, 0, stream>>>(h0, hh, seg_ptr, qstar, W_pred, b_pred, out);
        else
            k_attn<true><<<N_B, 128, 0, stream>>>(h0, hh, seg_ptr, qstar, W_pred, b_pred, out);
    }
}

// Round 7
// 513.982 us; speedup vs baseline: 1.8650x; 1.1348x over previous
//
#include <hip/hip_runtime.h>
#include <math.h>
#include <float.h>

#define N_NODES 50000
#define N_EDGES 800000
#define D_INP   96
#define D_HID   128
#define N_B     512
#define SCAN_NB 98   // ceil(50000/512)

// ---------------------------------------------------------------------------
// Weight prep + zero cnt.
// Wt_in[k][d] = W_in[d][k]                       (96 x 128)
// Wt2[k][g], k<128:  W_ih[g][k] + W_hh[g][k]     (fold q=hh algebra)
//            k>=128: W_ih[g][k]                  (r columns)   (256 x 512)
__global__ void k_transpose(const float* __restrict__ W_in,
                            const float* __restrict__ W_ih,
                            const float* __restrict__ W_hh,
                            float* __restrict__ Wt_in,
                            float* __restrict__ Wt2,
                            int* __restrict__ cnt) {
    int idx = blockIdx.x * 256 + threadIdx.x;
    if (idx < N_NODES) cnt[idx] = 0;
    if (idx < D_INP * D_HID) {
        int k = idx / D_HID, d = idx % D_HID;
        Wt_in[idx] = W_in[d * D_INP + k];
    }
    if (idx < 256 * 512) {
        int k = idx / 512, g = idx % 512;
        float v = W_ih[g * 256 + k];
        if (k < 128) v += W_hh[g * 128 + k];
        Wt2[idx] = v;
    }
}

// ---------------------------------------------------------------------------
// In-degree count; also builds seg_ptr (folded)
__global__ void k_count(const int* __restrict__ dst, int* __restrict__ cnt,
                        const int* __restrict__ batch, int* __restrict__ seg_ptr) {
    int e = blockIdx.x * 256 + threadIdx.x;
    if (e < N_EDGES) atomicAdd(&cnt[dst[e]], 1);
    if (e < N_NODES) {
        int n = e;
        int bc = batch[n];
        int bp = (n == 0) ? -1 : batch[n - 1];
        for (int b = bp + 1; b <= bc; b++) seg_ptr[b] = n;
        if (n == N_NODES - 1)
            for (int b = bc + 1; b <= N_B; b++) seg_ptr[b] = N_NODES;
    }
}

__global__ __launch_bounds__(512) void k_scan_block(const int* __restrict__ cnt,
                                                    int* __restrict__ row_ptr,
                                                    int* __restrict__ partials,
                                                    float* __restrict__ deg_f) {
    __shared__ int sm[512];
    int i = blockIdx.x * 512 + threadIdx.x;
    int v = (i < N_NODES) ? cnt[i] : 0;
    sm[threadIdx.x] = v;
    __syncthreads();
    for (int off = 1; off < 512; off <<= 1) {
        int u = (threadIdx.x >= off) ? sm[threadIdx.x - off] : 0;
        __syncthreads();
        sm[threadIdx.x] += u;
        __syncthreads();
    }
    if (i < N_NODES) {
        row_ptr[i] = sm[threadIdx.x] - v;
        deg_f[i] = (float)max(v, 1);
    }
    if (threadIdx.x == 511) partials[blockIdx.x] = sm[511];
}

// Merged: each block self-scans the 98 partials, adds its offset,
// re-zeroes cnt; last block writes row_ptr[N].
__global__ __launch_bounds__(512) void k_scan_add2(int* __restrict__ row_ptr,
                                                   const int* __restrict__ partials,
                                                   int* __restrict__ cnt) {
    __shared__ int sm[128];
    int t = threadIdx.x;
    int bid = blockIdx.x;
    if (t < 128) sm[t] = (t < SCAN_NB) ? partials[t] : 0;
    __syncthreads();
    for (int off = 1; off < 128; off <<= 1) {
        int u = (t >= off && t < 128) ? sm[t - off] : 0;
        __syncthreads();
        if (t < 128) sm[t] += u;
        __syncthreads();
    }
    int offset = (bid == 0) ? 0 : sm[bid - 1];   // exclusive prefix (inclusive scan)
    int i = bid * 512 + t;
    if (i < N_NODES) {
        row_ptr[i] += offset;
        cnt[i] = 0;
    }
    if (bid == SCAN_NB - 1 && t == 0) row_ptr[N_NODES] = sm[SCAN_NB - 1];
}

__global__ void k_scatter(const int* __restrict__ src, const int* __restrict__ dst,
                          const int* __restrict__ row_ptr, int* __restrict__ cnt,
                          int* __restrict__ esrc) {
    int e = blockIdx.x * 256 + threadIdx.x;
    if (e < N_EDGES) {
        int d = dst[e];
        int p = row_ptr[d] + atomicAdd(&cnt[d], 1);
        esrc[p] = src[e];
    }
}

// ---------------------------------------------------------------------------
// Input layer (row-major out).
__global__ __launch_bounds__(256) void k_ingemm(const float* __restrict__ x,
                                                const float* __restrict__ Wt_in,
                                                const float* __restrict__ b_in,
                                                float* __restrict__ h) {
    __shared__ __align__(16) float xs[64 * 96];
    __shared__ __align__(16) float ws[96 * 64];
    int n0 = blockIdx.x * 64;
    int d0 = blockIdx.y * 64;
    int tid = threadIdx.x;
    for (int j = tid; j < 64 * 96 / 4; j += 256) {
        int node = n0 + (j * 4) / 96;
        float4 v = make_float4(0.f, 0.f, 0.f, 0.f);
        if (node < N_NODES) v = *(const float4*)&x[n0 * 96 + j * 4];
        *(float4*)&xs[j * 4] = v;
    }
    for (int j = tid; j < 96 * 64 / 4; j += 256) {
        int k = (j * 4) / 64, dd = (j * 4) % 64;
        *(float4*)&ws[j * 4] = *(const float4*)&Wt_in[k * D_HID + d0 + dd];
    }
    __syncthreads();
    int tn = tid / 16;
    int td = tid % 16;
    float acc[4][4] = {};
    for (int k0 = 0; k0 < 96; k0 += 4) {
        float4 w0 = *(float4*)&ws[(k0 + 0) * 64 + td * 4];
        float4 w1 = *(float4*)&ws[(k0 + 1) * 64 + td * 4];
        float4 w2 = *(float4*)&ws[(k0 + 2) * 64 + td * 4];
        float4 w3 = *(float4*)&ws[(k0 + 3) * 64 + td * 4];
#pragma unroll
        for (int j = 0; j < 4; j++) {
            float4 xv = *(float4*)&xs[(tn * 4 + j) * 96 + k0];
            acc[j][0] += xv.x * w0.x + xv.y * w1.x + xv.z * w2.x + xv.w * w3.x;
            acc[j][1] += xv.x * w0.y + xv.y * w1.y + xv.z * w2.y + xv.w * w3.y;
            acc[j][2] += xv.x * w0.z + xv.y * w1.z + xv.z * w2.z + xv.w * w3.z;
            acc[j][3] += xv.x * w0.w + xv.y * w1.w + xv.z * w2.w + xv.w * w3.w;
        }
    }
    float4 bb = *(const float4*)&b_in[d0 + td * 4];
#pragma unroll
    for (int j = 0; j < 4; j++) {
        int node = n0 + tn * 4 + j;
        if (node < N_NODES) {
            float4 o;
            o.x = fmaxf(acc[j][0] + bb.x, 0.f);
            o.y = fmaxf(acc[j][1] + bb.y, 0.f);
            o.z = fmaxf(acc[j][2] + bb.z, 0.f);
            o.w = fmaxf(acc[j][3] + bb.w, 0.f);
            *(float4*)&h[(size_t)node * D_HID + d0 + td * 4] = o;
        }
    }
}

// ---------------------------------------------------------------------------
// MPNN step (R4's unroll x4 version: best measured, 28 VGPR).
__global__ __launch_bounds__(256) void k_mpnn(const float* __restrict__ hin,
                                              float* __restrict__ hout,
                                              const int* __restrict__ row_ptr,
                                              const int* __restrict__ esrc,
                                              const float* __restrict__ deg_f) {
    int g = threadIdx.x >> 5;
    int l = threadIdx.x & 31;
    int n = blockIdx.x * 8 + g;
    if (n >= N_NODES) return;
    int s0 = row_ptr[n], s1 = row_ptr[n + 1];
    float4 a0 = {0,0,0,0}, a1 = {0,0,0,0}, a2 = {0,0,0,0}, a3 = {0,0,0,0};
    int i = s0;
    for (; i + 4 <= s1; i += 4) {
        int e0 = esrc[i + 0];
        int e1 = esrc[i + 1];
        int e2 = esrc[i + 2];
        int e3 = esrc[i + 3];
        float4 v0 = *(const float4*)&hin[(size_t)e0 * 128 + l * 4];
        float4 v1 = *(const float4*)&hin[(size_t)e1 * 128 + l * 4];
        float4 v2 = *(const float4*)&hin[(size_t)e2 * 128 + l * 4];
        float4 v3 = *(const float4*)&hin[(size_t)e3 * 128 + l * 4];
        a0.x += v0.x; a0.y += v0.y; a0.z += v0.z; a0.w += v0.w;
        a1.x += v1.x; a1.y += v1.y; a1.z += v1.z; a1.w += v1.w;
        a2.x += v2.x; a2.y += v2.y; a2.z += v2.z; a2.w += v2.w;
        a3.x += v3.x; a3.y += v3.y; a3.z += v3.z; a3.w += v3.w;
    }
    for (; i < s1; i++) {
        int e0 = esrc[i];
        float4 v0 = *(const float4*)&hin[(size_t)e0 * 128 + l * 4];
        a0.x += v0.x; a0.y += v0.y; a0.z += v0.z; a0.w += v0.w;
    }
    a0.x += a1.x + a2.x + a3.x;
    a0.y += a1.y + a2.y + a3.y;
    a0.z += a1.z + a2.z + a3.z;
    a0.w += a1.w + a2.w + a3.w;
    float invd = 1.0f / deg_f[n];
    float4 hv = *(const float4*)&hin[(size_t)n * 128 + l * 4];
    float4 o;
    o.x = (hv.x + a0.x * invd) * 0.5f;
    o.y = (hv.y + a0.y * invd) * 0.5f;
    o.z = (hv.z + a0.z * invd) * 0.5f;
    o.w = (hv.w + a0.w * invd) * 0.5f;
    *(float4*)&hout[(size_t)n * 128 + l * 4] = o;
}

__device__ __forceinline__ float sigmoidf_(float v) { return 1.0f / (1.0f + expf(-v)); }

// ---------------------------------------------------------------------------
// Fully fused Set2Set, NO grid sync: per-graph recurrence is independent,
// so one block owns 2 graphs and keeps hh|r|cc state in LDS across all
// 3 steps. K=256 combined weight (q=hh folded into W_ih+W_hh).
// 256 blocks x 256 threads; waves 0-1 = graph row 0, waves 2-3 = row 1.
__global__ __launch_bounds__(256) void k_s2s2(const float* __restrict__ Wt2,
                                              const float* __restrict__ b_ih,
                                              const float* __restrict__ b_hh,
                                              const float* __restrict__ h,
                                              const int* __restrict__ seg_ptr,
                                              const float* __restrict__ W_pred,
                                              const float* __restrict__ b_pred,
                                              float* __restrict__ out) {
    __shared__ __align__(16) float in_s[2 * 256];   // [row][ hh(128) | r(128) ]
    __shared__ __align__(16) float c_s[2 * 128];
    __shared__ __align__(16) float gates_s[2 * 512];
    __shared__ float smax_s[2][4];
    __shared__ float ssum_s[2][4];
    __shared__ __align__(16) float sr_s[2][4][128];

    int t = threadIdx.x;
    // zero state
    in_s[t] = 0.f; in_s[256 + t] = 0.f;
    if (t < 256) c_s[t] = 0.f;

    int row = t >> 7;            // graph within block
    int loc = t & 127;
    int gq  = loc >> 5;          // 4 groups of 32 lanes per graph
    int l   = loc & 31;
    int b   = blockIdx.x * 2 + row;
    int s0 = seg_ptr[b], s1 = seg_ptr[b + 1];

    float2 bia;
    bia.x = b_ih[2 * t] + b_hh[2 * t];
    bia.y = b_ih[2 * t + 1] + b_hh[2 * t + 1];

    for (int step = 0; step < 3; step++) {
        __syncthreads();
        // ---- gates GEMM: thread t computes gates (2t, 2t+1) for BOTH rows
        float2 acc0 = {0.f, 0.f}, acc1 = {0.f, 0.f};
#pragma unroll 4
        for (int k = 0; k < 256; k++) {
            float2 w = *(const float2*)&Wt2[k * 512 + 2 * t];
            float a0 = in_s[k];
            float a1 = in_s[256 + k];
            acc0.x += a0 * w.x; acc0.y += a0 * w.y;
            acc1.x += a1 * w.x; acc1.y += a1 * w.y;
        }
        gates_s[2 * t]           = acc0.x + bia.x;
        gates_s[2 * t + 1]       = acc0.y + bia.y;
        gates_s[512 + 2 * t]     = acc1.x + bia.x;
        gates_s[512 + 2 * t + 1] = acc1.y + bia.y;
        __syncthreads();
        // ---- LSTM: thread t -> (row, feature loc)
        {
            float ig = gates_s[row * 512 + loc];
            float fg = gates_s[row * 512 + 128 + loc];
            float gg = gates_s[row * 512 + 256 + loc];
            float og = gates_s[row * 512 + 384 + loc];
            float c = sigmoidf_(fg) * c_s[row * 128 + loc] + sigmoidf_(ig) * tanhf(gg);
            c_s[row * 128 + loc] = c;
            in_s[row * 256 + loc] = sigmoidf_(og) * tanhf(c);   // hh (= q)
        }
        __syncthreads();
        // ---- attention (online softmax) over this row's segment
        float4 q = *(float4*)&in_s[row * 256 + l * 4];
        float M = -INFINITY, asum = 0.f;
        float4 racc = make_float4(0.f, 0.f, 0.f, 0.f);
        for (int n = s0 + gq; n < s1; n += 4) {
            float4 hv = *(const float4*)&h[(size_t)n * 128 + l * 4];
            float d = hv.x * q.x + hv.y * q.y + hv.z * q.z + hv.w * q.w;
            for (int m = 16; m >= 1; m >>= 1) d += __shfl_xor(d, m, 64);
            float newM = fmaxf(M, d);
            float scale = expf(M - newM);
            float a = expf(d - newM);
            asum = asum * scale + a;
            racc.x = racc.x * scale + a * hv.x;
            racc.y = racc.y * scale + a * hv.y;
            racc.z = racc.z * scale + a * hv.z;
            racc.w = racc.w * scale + a * hv.w;
            M = newM;
        }
        if (l == 0) { smax_s[row][gq] = M; ssum_s[row][gq] = asum; }
        *(float4*)&sr_s[row][gq][l * 4] = racc;
        __syncthreads();
        if (gq == 0) {
            float Mx = fmaxf(fmaxf(smax_s[row][0], smax_s[row][1]),
                             fmaxf(smax_s[row][2], smax_s[row][3]));
            float4 o = make_float4(0.f, 0.f, 0.f, 0.f);
            if (Mx > -INFINITY) {
                float w0 = expf(smax_s[row][0] - Mx), w1 = expf(smax_s[row][1] - Mx);
                float w2 = expf(smax_s[row][2] - Mx), w3 = expf(smax_s[row][3] - Mx);
                float tot = ssum_s[row][0] * w0 + ssum_s[row][1] * w1
                          + ssum_s[row][2] * w2 + ssum_s[row][3] * w3;
                float inv = 1.0f / (tot + 1e-16f);
                float4 r0 = *(float4*)&sr_s[row][0][l * 4];
                float4 r1 = *(float4*)&sr_s[row][1][l * 4];
                float4 r2 = *(float4*)&sr_s[row][2][l * 4];
                float4 r3 = *(float4*)&sr_s[row][3][l * 4];
                o.x = (r0.x * w0 + r1.x * w1 + r2.x * w2 + r3.x * w3) * inv;
                o.y = (r0.y * w0 + r1.y * w1 + r2.y * w2 + r3.y * w3) * inv;
                o.z = (r0.z * w0 + r1.z * w1 + r2.z * w2 + r3.z * w3) * inv;
                o.w = (r0.w * w0 + r1.w * w1 + r2.w * w2 + r3.w * w3) * inv;
            }
            *(float4*)&in_s[row * 256 + 128 + l * 4] = o;   // r for next step
            if (step == 2) {
                float4 wq = *(const float4*)&W_pred[l * 4];
                float4 wr = *(const float4*)&W_pred[128 + l * 4];
                float d = q.x * wq.x + q.y * wq.y + q.z * wq.z + q.w * wq.w
                        + o.x * wr.x + o.y * wr.y + o.z * wr.z + o.w * wr.w;
                for (int m = 16; m >= 1; m >>= 1) d += __shfl_xor(d, m, 64);
                if (l == 0) out[b] = d + b_pred[0];
            }
        }
    }
}

// ---------------------------------------------------------------------------
extern "C" void kernel_launch(void* const* d_in, const int* in_sizes, int n_in,
                              void* d_out, int out_size, void* d_ws, size_t ws_size,
                              hipStream_t stream) {
    const float* x      = (const float*)d_in[0];
    const int*   edge   = (const int*)d_in[1];
    const int*   batch  = (const int*)d_in[2];
    const float* W_in   = (const float*)d_in[3];
    const float* b_in   = (const float*)d_in[4];
    const float* W_ih   = (const float*)d_in[5];
    const float* W_hh   = (const float*)d_in[6];
    const float* b_ih   = (const float*)d_in[7];
    const float* b_hh   = (const float*)d_in[8];
    const float* W_pred = (const float*)d_in[9];
    const float* b_pred = (const float*)d_in[10];
    float* out = (float*)d_out;

    const int* src = edge;
    const int* dst = edge + N_EDGES;

    float* f = (float*)d_ws;
    float* h0    = f;                     f += (size_t)N_NODES * D_HID;
    float* h1    = f;                     f += (size_t)N_NODES * D_HID;
    float* deg_f = f;                     f += N_NODES;
    float* Wt_in = f;                     f += D_INP * D_HID;
    float* Wt2   = f;                     f += 256 * 512;
    int* ip = (int*)f;
    int* row_ptr = ip;                    ip += N_NODES + 1;
    int* cnt     = ip;                    ip += N_NODES;
    int* esrc    = ip;                    ip += N_EDGES;
    int* seg_ptr = ip;                    ip += N_B + 1;
    int* partials = ip;                   ip += 128;

    // ---- CSR build + seg_ptr + weight prep (5 dispatches)
    k_transpose<<<768, 256, 0, stream>>>(W_in, W_ih, W_hh, Wt_in, Wt2, cnt);
    k_count<<<(N_EDGES + 255) / 256, 256, 0, stream>>>(dst, cnt, batch, seg_ptr);
    k_scan_block<<<SCAN_NB, 512, 0, stream>>>(cnt, row_ptr, partials, deg_f);
    k_scan_add2<<<SCAN_NB, 512, 0, stream>>>(row_ptr, partials, cnt);
    k_scatter<<<(N_EDGES + 255) / 256, 256, 0, stream>>>(src, dst, row_ptr, cnt, esrc);

    // ---- input layer
    k_ingemm<<<dim3((N_NODES + 63) / 64, 2), 256, 0, stream>>>(x, Wt_in, b_in, h0);

    // ---- 4 MPNN steps (ping-pong, ends in h0)
    int mb = (N_NODES + 7) / 8;
    k_mpnn<<<mb, 256, 0, stream>>>(h0, h1, row_ptr, esrc, deg_f);
    k_mpnn<<<mb, 256, 0, stream>>>(h1, h0, row_ptr, esrc, deg_f);
    k_mpnn<<<mb, 256, 0, stream>>>(h0, h1, row_ptr, esrc, deg_f);
    k_mpnn<<<mb, 256, 0, stream>>>(h1, h0, row_ptr, esrc, deg_f);

    // ---- fused Set2Set + head: per-graph independence, NO grid sync
    k_s2s2<<<N_B / 2, 256, 0, stream>>>(Wt2, b_ih, b_hh, h0, seg_ptr,
                                        W_pred, b_pred, out);
}

// Round 8
// 487.533 us; speedup vs baseline: 1.9662x; 1.0543x over previous
//
#include <hip/hip_runtime.h>
#include <math.h>
#include <float.h>

#define N_NODES 50000
#define N_EDGES 800000
#define D_INP   96
#define D_HID   128
#define N_B     512
#define SCAN_NB 98   // ceil(50000/512)

// ---------------------------------------------------------------------------
// Weight prep + zero cnt.
// Wt_in[k][d] = W_in[d][k]                       (96 x 128)
// Wt2[k][g], k<128:  W_ih[g][k] + W_hh[g][k]     (fold q=hh algebra)
//            k>=128: W_ih[g][k]                  (r columns)   (256 x 512)
__global__ void k_transpose(const float* __restrict__ W_in,
                            const float* __restrict__ W_ih,
                            const float* __restrict__ W_hh,
                            float* __restrict__ Wt_in,
                            float* __restrict__ Wt2,
                            int* __restrict__ cnt) {
    int idx = blockIdx.x * 256 + threadIdx.x;
    if (idx < N_NODES) cnt[idx] = 0;
    if (idx < D_INP * D_HID) {
        int k = idx / D_HID, d = idx % D_HID;
        Wt_in[idx] = W_in[d * D_INP + k];
    }
    if (idx < 256 * 512) {
        int k = idx / 512, g = idx % 512;
        float v = W_ih[g * 256 + k];
        if (k < 128) v += W_hh[g * 128 + k];
        Wt2[idx] = v;
    }
}

// ---------------------------------------------------------------------------
// In-degree count; also builds seg_ptr (folded)
__global__ void k_count(const int* __restrict__ dst, int* __restrict__ cnt,
                        const int* __restrict__ batch, int* __restrict__ seg_ptr) {
    int e = blockIdx.x * 256 + threadIdx.x;
    if (e < N_EDGES) atomicAdd(&cnt[dst[e]], 1);
    if (e < N_NODES) {
        int n = e;
        int bc = batch[n];
        int bp = (n == 0) ? -1 : batch[n - 1];
        for (int b = bp + 1; b <= bc; b++) seg_ptr[b] = n;
        if (n == N_NODES - 1)
            for (int b = bc + 1; b <= N_B; b++) seg_ptr[b] = N_NODES;
    }
}

__global__ __launch_bounds__(512) void k_scan_block(const int* __restrict__ cnt,
                                                    int* __restrict__ row_ptr,
                                                    int* __restrict__ partials,
                                                    float* __restrict__ deg_f) {
    __shared__ int sm[512];
    int i = blockIdx.x * 512 + threadIdx.x;
    int v = (i < N_NODES) ? cnt[i] : 0;
    sm[threadIdx.x] = v;
    __syncthreads();
    for (int off = 1; off < 512; off <<= 1) {
        int u = (threadIdx.x >= off) ? sm[threadIdx.x - off] : 0;
        __syncthreads();
        sm[threadIdx.x] += u;
        __syncthreads();
    }
    if (i < N_NODES) {
        row_ptr[i] = sm[threadIdx.x] - v;
        deg_f[i] = (float)max(v, 1);
    }
    if (threadIdx.x == 511) partials[blockIdx.x] = sm[511];
}

// Merged: each block self-scans the 98 partials, adds its offset,
// re-zeroes cnt; last block writes row_ptr[N].
__global__ __launch_bounds__(512) void k_scan_add2(int* __restrict__ row_ptr,
                                                   const int* __restrict__ partials,
                                                   int* __restrict__ cnt) {
    __shared__ int sm[128];
    int t = threadIdx.x;
    int bid = blockIdx.x;
    if (t < 128) sm[t] = (t < SCAN_NB) ? partials[t] : 0;
    __syncthreads();
    for (int off = 1; off < 128; off <<= 1) {
        int u = (t >= off && t < 128) ? sm[t - off] : 0;
        __syncthreads();
        if (t < 128) sm[t] += u;
        __syncthreads();
    }
    int offset = (bid == 0) ? 0 : sm[bid - 1];   // exclusive prefix (inclusive scan)
    int i = bid * 512 + t;
    if (i < N_NODES) {
        row_ptr[i] += offset;
        cnt[i] = 0;
    }
    if (bid == SCAN_NB - 1 && t == 0) row_ptr[N_NODES] = sm[SCAN_NB - 1];
}

__global__ void k_scatter(const int* __restrict__ src, const int* __restrict__ dst,
                          const int* __restrict__ row_ptr, int* __restrict__ cnt,
                          int* __restrict__ esrc) {
    int e = blockIdx.x * 256 + threadIdx.x;
    if (e < N_EDGES) {
        int d = dst[e];
        int p = row_ptr[d] + atomicAdd(&cnt[d], 1);
        esrc[p] = src[e];
    }
}

// ---------------------------------------------------------------------------
// Input layer (row-major out).
__global__ __launch_bounds__(256) void k_ingemm(const float* __restrict__ x,
                                                const float* __restrict__ Wt_in,
                                                const float* __restrict__ b_in,
                                                float* __restrict__ h) {
    __shared__ __align__(16) float xs[64 * 96];
    __shared__ __align__(16) float ws[96 * 64];
    int n0 = blockIdx.x * 64;
    int d0 = blockIdx.y * 64;
    int tid = threadIdx.x;
    for (int j = tid; j < 64 * 96 / 4; j += 256) {
        int node = n0 + (j * 4) / 96;
        float4 v = make_float4(0.f, 0.f, 0.f, 0.f);
        if (node < N_NODES) v = *(const float4*)&x[n0 * 96 + j * 4];
        *(float4*)&xs[j * 4] = v;
    }
    for (int j = tid; j < 96 * 64 / 4; j += 256) {
        int k = (j * 4) / 64, dd = (j * 4) % 64;
        *(float4*)&ws[j * 4] = *(const float4*)&Wt_in[k * D_HID + d0 + dd];
    }
    __syncthreads();
    int tn = tid / 16;
    int td = tid % 16;
    float acc[4][4] = {};
    for (int k0 = 0; k0 < 96; k0 += 4) {
        float4 w0 = *(float4*)&ws[(k0 + 0) * 64 + td * 4];
        float4 w1 = *(float4*)&ws[(k0 + 1) * 64 + td * 4];
        float4 w2 = *(float4*)&ws[(k0 + 2) * 64 + td * 4];
        float4 w3 = *(float4*)&ws[(k0 + 3) * 64 + td * 4];
#pragma unroll
        for (int j = 0; j < 4; j++) {
            float4 xv = *(float4*)&xs[(tn * 4 + j) * 96 + k0];
            acc[j][0] += xv.x * w0.x + xv.y * w1.x + xv.z * w2.x + xv.w * w3.x;
            acc[j][1] += xv.x * w0.y + xv.y * w1.y + xv.z * w2.y + xv.w * w3.y;
            acc[j][2] += xv.x * w0.z + xv.y * w1.z + xv.z * w2.z + xv.w * w3.z;
            acc[j][3] += xv.x * w0.w + xv.y * w1.w + xv.z * w2.w + xv.w * w3.w;
        }
    }
    float4 bb = *(const float4*)&b_in[d0 + td * 4];
#pragma unroll
    for (int j = 0; j < 4; j++) {
        int node = n0 + tn * 4 + j;
        if (node < N_NODES) {
            float4 o;
            o.x = fmaxf(acc[j][0] + bb.x, 0.f);
            o.y = fmaxf(acc[j][1] + bb.y, 0.f);
            o.z = fmaxf(acc[j][2] + bb.z, 0.f);
            o.w = fmaxf(acc[j][3] + bb.w, 0.f);
            *(float4*)&h[(size_t)node * D_HID + d0 + td * 4] = o;
        }
    }
}

// ---------------------------------------------------------------------------
// MPNN step (unroll x4: best measured, 28 VGPR).
__global__ __launch_bounds__(256) void k_mpnn(const float* __restrict__ hin,
                                              float* __restrict__ hout,
                                              const int* __restrict__ row_ptr,
                                              const int* __restrict__ esrc,
                                              const float* __restrict__ deg_f) {
    int g = threadIdx.x >> 5;
    int l = threadIdx.x & 31;
    int n = blockIdx.x * 8 + g;
    if (n >= N_NODES) return;
    int s0 = row_ptr[n], s1 = row_ptr[n + 1];
    float4 a0 = {0,0,0,0}, a1 = {0,0,0,0}, a2 = {0,0,0,0}, a3 = {0,0,0,0};
    int i = s0;
    for (; i + 4 <= s1; i += 4) {
        int e0 = esrc[i + 0];
        int e1 = esrc[i + 1];
        int e2 = esrc[i + 2];
        int e3 = esrc[i + 3];
        float4 v0 = *(const float4*)&hin[(size_t)e0 * 128 + l * 4];
        float4 v1 = *(const float4*)&hin[(size_t)e1 * 128 + l * 4];
        float4 v2 = *(const float4*)&hin[(size_t)e2 * 128 + l * 4];
        float4 v3 = *(const float4*)&hin[(size_t)e3 * 128 + l * 4];
        a0.x += v0.x; a0.y += v0.y; a0.z += v0.z; a0.w += v0.w;
        a1.x += v1.x; a1.y += v1.y; a1.z += v1.z; a1.w += v1.w;
        a2.x += v2.x; a2.y += v2.y; a2.z += v2.z; a2.w += v2.w;
        a3.x += v3.x; a3.y += v3.y; a3.z += v3.z; a3.w += v3.w;
    }
    for (; i < s1; i++) {
        int e0 = esrc[i];
        float4 v0 = *(const float4*)&hin[(size_t)e0 * 128 + l * 4];
        a0.x += v0.x; a0.y += v0.y; a0.z += v0.z; a0.w += v0.w;
    }
    a0.x += a1.x + a2.x + a3.x;
    a0.y += a1.y + a2.y + a3.y;
    a0.z += a1.z + a2.z + a3.z;
    a0.w += a1.w + a2.w + a3.w;
    float invd = 1.0f / deg_f[n];
    float4 hv = *(const float4*)&hin[(size_t)n * 128 + l * 4];
    float4 o;
    o.x = (hv.x + a0.x * invd) * 0.5f;
    o.y = (hv.y + a0.y * invd) * 0.5f;
    o.z = (hv.z + a0.z * invd) * 0.5f;
    o.w = (hv.w + a0.w * invd) * 0.5f;
    *(float4*)&hout[(size_t)n * 128 + l * 4] = o;
}

__device__ __forceinline__ float sigmoidf_(float v) { return 1.0f / (1.0f + expf(-v)); }

// ---------------------------------------------------------------------------
// Fused Set2Set v2: 512 threads/block, 2 graphs/block, 8 lane-groups/graph,
// attention unrolled x2 with independent online-softmax states.
// Thread t computes gate t for BOTH rows (Wt2 read once per block).
__global__ __launch_bounds__(512) void k_s2s2(const float* __restrict__ Wt2,
                                              const float* __restrict__ b_ih,
                                              const float* __restrict__ b_hh,
                                              const float* __restrict__ h,
                                              const int* __restrict__ seg_ptr,
                                              const float* __restrict__ W_pred,
                                              const float* __restrict__ b_pred,
                                              float* __restrict__ out) {
    __shared__ __align__(16) float in_s[2 * 256];   // [row][ hh(128) | r(128) ]
    __shared__ __align__(16) float c_s[2 * 128];
    __shared__ __align__(16) float gates_s[2 * 512];
    __shared__ float smax_s[2][8];
    __shared__ float ssum_s[2][8];
    __shared__ __align__(16) float sr_s[2][8][128];

    int t = threadIdx.x;
    in_s[t < 512 ? t : 0] = 0.f;          // t covers all 512 entries
    if (t < 256) c_s[t] = 0.f;

    int row = t >> 8;            // graph within block (attention mapping)
    int loc = t & 255;
    int gq  = loc >> 5;          // 8 groups of 32 lanes per graph
    int l   = t & 31;
    int b   = blockIdx.x * 2 + row;
    int s0 = seg_ptr[b], s1 = seg_ptr[b + 1];

    float bia = b_ih[t] + b_hh[t];        // gate id = t

    for (int step = 0; step < 3; step++) {
        __syncthreads();
        // ---- gates GEMM: thread t -> gate t for both rows
        float acc0 = 0.f, acc1 = 0.f;
#pragma unroll 8
        for (int k = 0; k < 256; k++) {
            float w = Wt2[k * 512 + t];
            acc0 += in_s[k] * w;
            acc1 += in_s[256 + k] * w;
        }
        gates_s[t] = acc0 + bia;
        gates_s[512 + t] = acc1 + bia;
        __syncthreads();
        // ---- LSTM: t < 256 -> (row r2, feature f)
        if (t < 256) {
            int r2 = t >> 7, f = t & 127;
            float ig = gates_s[r2 * 512 + f];
            float fg = gates_s[r2 * 512 + 128 + f];
            float gg = gates_s[r2 * 512 + 256 + f];
            float og = gates_s[r2 * 512 + 384 + f];
            float c = sigmoidf_(fg) * c_s[r2 * 128 + f] + sigmoidf_(ig) * tanhf(gg);
            c_s[r2 * 128 + f] = c;
            in_s[r2 * 256 + f] = sigmoidf_(og) * tanhf(c);   // hh (= q)
        }
        __syncthreads();
        // ---- attention: 8 groups/graph, 2 independent online states/group
        float4 q = *(float4*)&in_s[row * 256 + l * 4];
        float Ma = -INFINITY, sa = 0.f;
        float Mb = -INFINITY, sb = 0.f;
        float4 ra = make_float4(0.f, 0.f, 0.f, 0.f);
        float4 rb = make_float4(0.f, 0.f, 0.f, 0.f);
        for (int n = s0 + gq; n < s1; n += 16) {
            {
                float4 hv = *(const float4*)&h[(size_t)n * 128 + l * 4];
                float d = hv.x * q.x + hv.y * q.y + hv.z * q.z + hv.w * q.w;
                for (int m = 16; m >= 1; m >>= 1) d += __shfl_xor(d, m, 64);
                float nM = fmaxf(Ma, d);
                float sc = expf(Ma - nM);
                float a = expf(d - nM);
                sa = sa * sc + a;
                ra.x = ra.x * sc + a * hv.x;
                ra.y = ra.y * sc + a * hv.y;
                ra.z = ra.z * sc + a * hv.z;
                ra.w = ra.w * sc + a * hv.w;
                Ma = nM;
            }
            int n2 = n + 8;
            if (n2 < s1) {
                float4 hv = *(const float4*)&h[(size_t)n2 * 128 + l * 4];
                float d = hv.x * q.x + hv.y * q.y + hv.z * q.z + hv.w * q.w;
                for (int m = 16; m >= 1; m >>= 1) d += __shfl_xor(d, m, 64);
                float nM = fmaxf(Mb, d);
                float sc = expf(Mb - nM);
                float a = expf(d - nM);
                sb = sb * sc + a;
                rb.x = rb.x * sc + a * hv.x;
                rb.y = rb.y * sc + a * hv.y;
                rb.z = rb.z * sc + a * hv.z;
                rb.w = rb.w * sc + a * hv.w;
                Mb = nM;
            }
        }
        // merge the two states
        float M = fmaxf(Ma, Mb);
        float wa = (Ma > -INFINITY) ? expf(Ma - M) : 0.f;
        float wb = (Mb > -INFINITY) ? expf(Mb - M) : 0.f;
        float asum = sa * wa + sb * wb;
        float4 racc;
        racc.x = ra.x * wa + rb.x * wb;
        racc.y = ra.y * wa + rb.y * wb;
        racc.z = ra.z * wa + rb.z * wb;
        racc.w = ra.w * wa + rb.w * wb;
        if (l == 0) { smax_s[row][gq] = M; ssum_s[row][gq] = asum; }
        *(float4*)&sr_s[row][gq][l * 4] = racc;
        __syncthreads();
        if (gq == 0) {
            float Mx = -INFINITY;
#pragma unroll
            for (int i = 0; i < 8; i++) Mx = fmaxf(Mx, smax_s[row][i]);
            float4 o = make_float4(0.f, 0.f, 0.f, 0.f);
            if (Mx > -INFINITY) {
                float tot = 0.f;
                float4 osum = make_float4(0.f, 0.f, 0.f, 0.f);
#pragma unroll
                for (int i = 0; i < 8; i++) {
                    float wi = expf(smax_s[row][i] - Mx);   // -inf -> 0
                    tot += ssum_s[row][i] * wi;
                    float4 ri = *(float4*)&sr_s[row][i][l * 4];
                    osum.x += ri.x * wi; osum.y += ri.y * wi;
                    osum.z += ri.z * wi; osum.w += ri.w * wi;
                }
                float inv = 1.0f / (tot + 1e-16f);
                o.x = osum.x * inv; o.y = osum.y * inv;
                o.z = osum.z * inv; o.w = osum.w * inv;
            }
            *(float4*)&in_s[row * 256 + 128 + l * 4] = o;   // r for next step
            if (step == 2) {
                float4 wq = *(const float4*)&W_pred[l * 4];
                float4 wr = *(const float4*)&W_pred[128 + l * 4];
                float d = q.x * wq.x + q.y * wq.y + q.z * wq.z + q.w * wq.w
                        + o.x * wr.x + o.y * wr.y + o.z * wr.z + o.w * wr.w;
                for (int m = 16; m >= 1; m >>= 1) d += __shfl_xor(d, m, 64);
                if (l == 0) out[b] = d + b_pred[0];
            }
        }
    }
}

// ---------------------------------------------------------------------------
extern "C" void kernel_launch(void* const* d_in, const int* in_sizes, int n_in,
                              void* d_out, int out_size, void* d_ws, size_t ws_size,
                              hipStream_t stream) {
    const float* x      = (const float*)d_in[0];
    const int*   edge   = (const int*)d_in[1];
    const int*   batch  = (const int*)d_in[2];
    const float* W_in   = (const float*)d_in[3];
    const float* b_in   = (const float*)d_in[4];
    const float* W_ih   = (const float*)d_in[5];
    const float* W_hh   = (const float*)d_in[6];
    const float* b_ih   = (const float*)d_in[7];
    const float* b_hh   = (const float*)d_in[8];
    const float* W_pred = (const float*)d_in[9];
    const float* b_pred = (const float*)d_in[10];
    float* out = (float*)d_out;

    const int* src = edge;
    const int* dst = edge + N_EDGES;

    float* f = (float*)d_ws;
    float* h0    = f;                     f += (size_t)N_NODES * D_HID;
    float* h1    = f;                     f += (size_t)N_NODES * D_HID;
    float* deg_f = f;                     f += N_NODES;
    float* Wt_in = f;                     f += D_INP * D_HID;
    float* Wt2   = f;                     f += 256 * 512;
    int* ip = (int*)f;
    int* row_ptr = ip;                    ip += N_NODES + 1;
    int* cnt     = ip;                    ip += N_NODES;
    int* esrc    = ip;                    ip += N_EDGES;
    int* seg_ptr = ip;                    ip += N_B + 1;
    int* partials = ip;                   ip += 128;

    // ---- CSR build + seg_ptr + weight prep (5 dispatches)
    k_transpose<<<768, 256, 0, stream>>>(W_in, W_ih, W_hh, Wt_in, Wt2, cnt);
    k_count<<<(N_EDGES + 255) / 256, 256, 0, stream>>>(dst, cnt, batch, seg_ptr);
    k_scan_block<<<SCAN_NB, 512, 0, stream>>>(cnt, row_ptr, partials, deg_f);
    k_scan_add2<<<SCAN_NB, 512, 0, stream>>>(row_ptr, partials, cnt);
    k_scatter<<<(N_EDGES + 255) / 256, 256, 0, stream>>>(src, dst, row_ptr, cnt, esrc);

    // ---- input layer
    k_ingemm<<<dim3((N_NODES + 63) / 64, 2), 256, 0, stream>>>(x, Wt_in, b_in, h0);

    // ---- 4 MPNN steps (ping-pong, ends in h0)
    int mb = (N_NODES + 7) / 8;
    k_mpnn<<<mb, 256, 0, stream>>>(h0, h1, row_ptr, esrc, deg_f);
    k_mpnn<<<mb, 256, 0, stream>>>(h1, h0, row_ptr, esrc, deg_f);
    k_mpnn<<<mb, 256, 0, stream>>>(h0, h1, row_ptr, esrc, deg_f);
    k_mpnn<<<mb, 256, 0, stream>>>(h1, h0, row_ptr, esrc, deg_f);

    // ---- fused Set2Set + head: per-graph independence, NO grid sync
    k_s2s2<<<N_B / 2, 512, 0, stream>>>(Wt2, b_ih, b_hh, h0, seg_ptr,
                                        W_pred, b_pred, out);
}

// Round 9
// 462.110 us; speedup vs baseline: 2.0743x; 1.0550x over previous
//
#include <hip/hip_runtime.h>
#include <math.h>
#include <float.h>

#define N_NODES 50000
#define N_EDGES 800000
#define D_INP   96
#define D_HID   128
#define N_B     512
#define CAP     64            // bucket capacity; in-degree ~Poisson(16), P(>64)~1e-17

// ---------------------------------------------------------------------------
// Weight prep + zero cnt.
// Wt_in[k][d] = W_in[d][k]                       (96 x 128)
// Wt2[k][g], k<128:  W_ih[g][k] + W_hh[g][k]     (fold q=hh algebra)
//            k>=128: W_ih[g][k]                  (r columns)   (256 x 512)
__global__ void k_prep(const float* __restrict__ W_in,
                       const float* __restrict__ W_ih,
                       const float* __restrict__ W_hh,
                       float* __restrict__ Wt_in,
                       float* __restrict__ Wt2,
                       int* __restrict__ cnt) {
    int idx = blockIdx.x * 256 + threadIdx.x;
    if (idx < N_NODES) cnt[idx] = 0;
    if (idx < D_INP * D_HID) {
        int k = idx / D_HID, d = idx % D_HID;
        Wt_in[idx] = W_in[d * D_INP + k];
    }
    if (idx < 256 * 512) {
        int k = idx / 512, g = idx % 512;
        float v = W_ih[g * 256 + k];
        if (k < 128) v += W_hh[g * 128 + k];
        Wt2[idx] = v;
    }
}

// ---------------------------------------------------------------------------
// FAT kernel: blocks [0, B_GEMM) do the input GEMM; blocks [B_GEMM, ..) do
// single-pass edge bucketing + seg_ptr build. The two parts are independent
// (both depend only on k_prep) and overlap VALU/LDS work with atomics.
#define B_GEMM_X 782          // ceil(50000/64)
#define B_GEMM   (B_GEMM_X * 2)
#define B_BUCKET 3125         // ceil(800000/256)

__global__ __launch_bounds__(256) void k_fat(const float* __restrict__ x,
                                             const float* __restrict__ Wt_in,
                                             const float* __restrict__ b_in,
                                             float* __restrict__ h,
                                             const int* __restrict__ src,
                                             const int* __restrict__ dst,
                                             const int* __restrict__ batch,
                                             int* __restrict__ cnt,
                                             int* __restrict__ esrc,
                                             int* __restrict__ seg_ptr) {
    int bid = blockIdx.x;
    int tid = threadIdx.x;
    if (bid >= B_GEMM) {
        // ---------------- bucket part ----------------
        int e = (bid - B_GEMM) * 256 + tid;
        if (e < N_EDGES) {
            int d = dst[e];
            int p = atomicAdd(&cnt[d], 1);
            if (p < CAP) esrc[d * CAP + p] = src[e];
        }
        if (e < N_NODES) {
            int n = e;
            int bc = batch[n];
            int bp = (n == 0) ? -1 : batch[n - 1];
            for (int b = bp + 1; b <= bc; b++) seg_ptr[b] = n;
            if (n == N_NODES - 1)
                for (int b = bc + 1; b <= N_B; b++) seg_ptr[b] = N_NODES;
        }
        return;
    }
    // ---------------- GEMM part ----------------
    __shared__ __align__(16) float xs[64 * 96];
    __shared__ __align__(16) float ws[96 * 64];
    int n0 = (bid % B_GEMM_X) * 64;
    int d0 = (bid / B_GEMM_X) * 64;
    for (int j = tid; j < 64 * 96 / 4; j += 256) {
        int node = n0 + (j * 4) / 96;
        float4 v = make_float4(0.f, 0.f, 0.f, 0.f);
        if (node < N_NODES) v = *(const float4*)&x[n0 * 96 + j * 4];
        *(float4*)&xs[j * 4] = v;
    }
    for (int j = tid; j < 96 * 64 / 4; j += 256) {
        int k = (j * 4) / 64, dd = (j * 4) % 64;
        *(float4*)&ws[j * 4] = *(const float4*)&Wt_in[k * D_HID + d0 + dd];
    }
    __syncthreads();
    int tn = tid / 16;
    int td = tid % 16;
    float acc[4][4] = {};
    for (int k0 = 0; k0 < 96; k0 += 4) {
        float4 w0 = *(float4*)&ws[(k0 + 0) * 64 + td * 4];
        float4 w1 = *(float4*)&ws[(k0 + 1) * 64 + td * 4];
        float4 w2 = *(float4*)&ws[(k0 + 2) * 64 + td * 4];
        float4 w3 = *(float4*)&ws[(k0 + 3) * 64 + td * 4];
#pragma unroll
        for (int j = 0; j < 4; j++) {
            float4 xv = *(float4*)&xs[(tn * 4 + j) * 96 + k0];
            acc[j][0] += xv.x * w0.x + xv.y * w1.x + xv.z * w2.x + xv.w * w3.x;
            acc[j][1] += xv.x * w0.y + xv.y * w1.y + xv.z * w2.y + xv.w * w3.y;
            acc[j][2] += xv.x * w0.z + xv.y * w1.z + xv.z * w2.z + xv.w * w3.z;
            acc[j][3] += xv.x * w0.w + xv.y * w1.w + xv.z * w2.w + xv.w * w3.w;
        }
    }
    float4 bb = *(const float4*)&b_in[d0 + td * 4];
#pragma unroll
    for (int j = 0; j < 4; j++) {
        int node = n0 + tn * 4 + j;
        if (node < N_NODES) {
            float4 o;
            o.x = fmaxf(acc[j][0] + bb.x, 0.f);
            o.y = fmaxf(acc[j][1] + bb.y, 0.f);
            o.z = fmaxf(acc[j][2] + bb.z, 0.f);
            o.w = fmaxf(acc[j][3] + bb.w, 0.f);
            *(float4*)&h[(size_t)node * D_HID + d0 + td * 4] = o;
        }
    }
}

// ---------------------------------------------------------------------------
// MPNN step (unroll x4). Bucketed esrc: row n at esrc[n*CAP], length cnt[n].
__global__ __launch_bounds__(256) void k_mpnn(const float* __restrict__ hin,
                                              float* __restrict__ hout,
                                              const int* __restrict__ cnt,
                                              const int* __restrict__ esrc) {
    int g = threadIdx.x >> 5;
    int l = threadIdx.x & 31;
    int n = blockIdx.x * 8 + g;
    if (n >= N_NODES) return;
    int deg = cnt[n];
    int len = min(deg, CAP);
    const int* row = &esrc[n * CAP];
    float4 a0 = {0,0,0,0}, a1 = {0,0,0,0}, a2 = {0,0,0,0}, a3 = {0,0,0,0};
    int i = 0;
    for (; i + 4 <= len; i += 4) {
        int e0 = row[i + 0];
        int e1 = row[i + 1];
        int e2 = row[i + 2];
        int e3 = row[i + 3];
        float4 v0 = *(const float4*)&hin[(size_t)e0 * 128 + l * 4];
        float4 v1 = *(const float4*)&hin[(size_t)e1 * 128 + l * 4];
        float4 v2 = *(const float4*)&hin[(size_t)e2 * 128 + l * 4];
        float4 v3 = *(const float4*)&hin[(size_t)e3 * 128 + l * 4];
        a0.x += v0.x; a0.y += v0.y; a0.z += v0.z; a0.w += v0.w;
        a1.x += v1.x; a1.y += v1.y; a1.z += v1.z; a1.w += v1.w;
        a2.x += v2.x; a2.y += v2.y; a2.z += v2.z; a2.w += v2.w;
        a3.x += v3.x; a3.y += v3.y; a3.z += v3.z; a3.w += v3.w;
    }
    for (; i < len; i++) {
        int e0 = row[i];
        float4 v0 = *(const float4*)&hin[(size_t)e0 * 128 + l * 4];
        a0.x += v0.x; a0.y += v0.y; a0.z += v0.z; a0.w += v0.w;
    }
    a0.x += a1.x + a2.x + a3.x;
    a0.y += a1.y + a2.y + a3.y;
    a0.z += a1.z + a2.z + a3.z;
    a0.w += a1.w + a2.w + a3.w;
    float invd = 1.0f / (float)max(deg, 1);
    float4 hv = *(const float4*)&hin[(size_t)n * 128 + l * 4];
    float4 o;
    o.x = (hv.x + a0.x * invd) * 0.5f;
    o.y = (hv.y + a0.y * invd) * 0.5f;
    o.z = (hv.z + a0.z * invd) * 0.5f;
    o.w = (hv.w + a0.w * invd) * 0.5f;
    *(float4*)&hout[(size_t)n * 128 + l * 4] = o;
}

__device__ __forceinline__ float sigmoidf_(float v) { return 1.0f / (1.0f + expf(-v)); }

// ---------------------------------------------------------------------------
// Fused Set2Set: 512 threads/block, 2 graphs/block, 8 lane-groups/graph,
// attention unrolled x2 with independent online-softmax states.
__global__ __launch_bounds__(512) void k_s2s2(const float* __restrict__ Wt2,
                                              const float* __restrict__ b_ih,
                                              const float* __restrict__ b_hh,
                                              const float* __restrict__ h,
                                              const int* __restrict__ seg_ptr,
                                              const float* __restrict__ W_pred,
                                              const float* __restrict__ b_pred,
                                              float* __restrict__ out) {
    __shared__ __align__(16) float in_s[2 * 256];   // [row][ hh(128) | r(128) ]
    __shared__ __align__(16) float c_s[2 * 128];
    __shared__ __align__(16) float gates_s[2 * 512];
    __shared__ float smax_s[2][8];
    __shared__ float ssum_s[2][8];
    __shared__ __align__(16) float sr_s[2][8][128];

    int t = threadIdx.x;
    in_s[t] = 0.f;
    if (t < 256) c_s[t] = 0.f;

    int row = t >> 8;
    int loc = t & 255;
    int gq  = loc >> 5;
    int l   = t & 31;
    int b   = blockIdx.x * 2 + row;
    int s0 = seg_ptr[b], s1 = seg_ptr[b + 1];

    float bia = b_ih[t] + b_hh[t];

    for (int step = 0; step < 3; step++) {
        __syncthreads();
        float acc0 = 0.f, acc1 = 0.f;
#pragma unroll 8
        for (int k = 0; k < 256; k++) {
            float w = Wt2[k * 512 + t];
            acc0 += in_s[k] * w;
            acc1 += in_s[256 + k] * w;
        }
        gates_s[t] = acc0 + bia;
        gates_s[512 + t] = acc1 + bia;
        __syncthreads();
        if (t < 256) {
            int r2 = t >> 7, f = t & 127;
            float ig = gates_s[r2 * 512 + f];
            float fg = gates_s[r2 * 512 + 128 + f];
            float gg = gates_s[r2 * 512 + 256 + f];
            float og = gates_s[r2 * 512 + 384 + f];
            float c = sigmoidf_(fg) * c_s[r2 * 128 + f] + sigmoidf_(ig) * tanhf(gg);
            c_s[r2 * 128 + f] = c;
            in_s[r2 * 256 + f] = sigmoidf_(og) * tanhf(c);
        }
        __syncthreads();
        float4 q = *(float4*)&in_s[row * 256 + l * 4];
        float Ma = -INFINITY, sa = 0.f;
        float Mb = -INFINITY, sb = 0.f;
        float4 ra = make_float4(0.f, 0.f, 0.f, 0.f);
        float4 rb = make_float4(0.f, 0.f, 0.f, 0.f);
        for (int n = s0 + gq; n < s1; n += 16) {
            {
                float4 hv = *(const float4*)&h[(size_t)n * 128 + l * 4];
                float d = hv.x * q.x + hv.y * q.y + hv.z * q.z + hv.w * q.w;
                for (int m = 16; m >= 1; m >>= 1) d += __shfl_xor(d, m, 64);
                float nM = fmaxf(Ma, d);
                float sc = expf(Ma - nM);
                float a = expf(d - nM);
                sa = sa * sc + a;
                ra.x = ra.x * sc + a * hv.x;
                ra.y = ra.y * sc + a * hv.y;
                ra.z = ra.z * sc + a * hv.z;
                ra.w = ra.w * sc + a * hv.w;
                Ma = nM;
            }
            int n2 = n + 8;
            if (n2 < s1) {
                float4 hv = *(const float4*)&h[(size_t)n2 * 128 + l * 4];
                float d = hv.x * q.x + hv.y * q.y + hv.z * q.z + hv.w * q.w;
                for (int m = 16; m >= 1; m >>= 1) d += __shfl_xor(d, m, 64);
                float nM = fmaxf(Mb, d);
                float sc = expf(Mb - nM);
                float a = expf(d - nM);
                sb = sb * sc + a;
                rb.x = rb.x * sc + a * hv.x;
                rb.y = rb.y * sc + a * hv.y;
                rb.z = rb.z * sc + a * hv.z;
                rb.w = rb.w * sc + a * hv.w;
                Mb = nM;
            }
        }
        float M = fmaxf(Ma, Mb);
        float wa = (Ma > -INFINITY) ? expf(Ma - M) : 0.f;
        float wb = (Mb > -INFINITY) ? expf(Mb - M) : 0.f;
        float asum = sa * wa + sb * wb;
        float4 racc;
        racc.x = ra.x * wa + rb.x * wb;
        racc.y = ra.y * wa + rb.y * wb;
        racc.z = ra.z * wa + rb.z * wb;
        racc.w = ra.w * wa + rb.w * wb;
        if (l == 0) { smax_s[row][gq] = M; ssum_s[row][gq] = asum; }
        *(float4*)&sr_s[row][gq][l * 4] = racc;
        __syncthreads();
        if (gq == 0) {
            float Mx = -INFINITY;
#pragma unroll
            for (int i = 0; i < 8; i++) Mx = fmaxf(Mx, smax_s[row][i]);
            float4 o = make_float4(0.f, 0.f, 0.f, 0.f);
            if (Mx > -INFINITY) {
                float tot = 0.f;
                float4 osum = make_float4(0.f, 0.f, 0.f, 0.f);
#pragma unroll
                for (int i = 0; i < 8; i++) {
                    float wi = expf(smax_s[row][i] - Mx);
                    tot += ssum_s[row][i] * wi;
                    float4 ri = *(float4*)&sr_s[row][i][l * 4];
                    osum.x += ri.x * wi; osum.y += ri.y * wi;
                    osum.z += ri.z * wi; osum.w += ri.w * wi;
                }
                float inv = 1.0f / (tot + 1e-16f);
                o.x = osum.x * inv; o.y = osum.y * inv;
                o.z = osum.z * inv; o.w = osum.w * inv;
            }
            *(float4*)&in_s[row * 256 + 128 + l * 4] = o;
            if (step == 2) {
                float4 wq = *(const float4*)&W_pred[l * 4];
                float4 wr = *(const float4*)&W_pred[128 + l * 4];
                float d = q.x * wq.x + q.y * wq.y + q.z * wq.z + q.w * wq.w
                        + o.x * wr.x + o.y * wr.y + o.z * wr.z + o.w * wr.w;
                for (int m = 16; m >= 1; m >>= 1) d += __shfl_xor(d, m, 64);
                if (l == 0) out[b] = d + b_pred[0];
            }
        }
    }
}

// ---------------------------------------------------------------------------
extern "C" void kernel_launch(void* const* d_in, const int* in_sizes, int n_in,
                              void* d_out, int out_size, void* d_ws, size_t ws_size,
                              hipStream_t stream) {
    const float* x      = (const float*)d_in[0];
    const int*   edge   = (const int*)d_in[1];
    const int*   batch  = (const int*)d_in[2];
    const float* W_in   = (const float*)d_in[3];
    const float* b_in   = (const float*)d_in[4];
    const float* W_ih   = (const float*)d_in[5];
    const float* W_hh   = (const float*)d_in[6];
    const float* b_ih   = (const float*)d_in[7];
    const float* b_hh   = (const float*)d_in[8];
    const float* W_pred = (const float*)d_in[9];
    const float* b_pred = (const float*)d_in[10];
    float* out = (float*)d_out;

    const int* src = edge;
    const int* dst = edge + N_EDGES;

    float* f = (float*)d_ws;
    float* h0    = f;                     f += (size_t)N_NODES * D_HID;
    float* h1    = f;                     f += (size_t)N_NODES * D_HID;
    float* Wt_in = f;                     f += D_INP * D_HID;
    float* Wt2   = f;                     f += 256 * 512;
    int* ip = (int*)f;
    int* cnt     = ip;                    ip += N_NODES;
    int* seg_ptr = ip;                    ip += N_B + 1 + 3;   // keep alignment
    int* esrc    = ip;                    ip += (size_t)N_NODES * CAP;

    // ---- weight prep + cnt zero (1 dispatch)
    k_prep<<<768, 256, 0, stream>>>(W_in, W_ih, W_hh, Wt_in, Wt2, cnt);

    // ---- FAT: input GEMM || edge bucketing + seg_ptr (1 dispatch)
    k_fat<<<B_GEMM + B_BUCKET, 256, 0, stream>>>(x, Wt_in, b_in, h0,
                                                 src, dst, batch,
                                                 cnt, esrc, seg_ptr);

    // ---- 4 MPNN steps (ping-pong, ends in h0)
    int mb = (N_NODES + 7) / 8;
    k_mpnn<<<mb, 256, 0, stream>>>(h0, h1, cnt, esrc);
    k_mpnn<<<mb, 256, 0, stream>>>(h1, h0, cnt, esrc);
    k_mpnn<<<mb, 256, 0, stream>>>(h0, h1, cnt, esrc);
    k_mpnn<<<mb, 256, 0, stream>>>(h1, h0, cnt, esrc);

    // ---- fused Set2Set + head
    k_s2s2<<<N_B / 2, 512, 0, stream>>>(Wt2, b_ih, b_hh, h0, seg_ptr,
                                        W_pred, b_pred, out);
}

// Round 10
// 443.703 us; speedup vs baseline: 2.1604x; 1.0415x over previous
//
#include <hip/hip_runtime.h>
#include <math.h>
#include <float.h>

#define N_NODES 50000
#define N_EDGES 800000
#define D_INP   96
#define D_HID   128
#define N_B     512
#define CAP     64            // bucket capacity; in-degree ~Poisson(16), P(>64)~1e-17
#define XS_LD   100           // padded leading dim: 4-way LDS conflict -> free 2-way

// ---------------------------------------------------------------------------
// Weight prep + zero cnt.
// Wt_in[k][d] = W_in[d][k]                       (96 x 128)
// Wt2[k][g], k<128:  W_ih[g][k] + W_hh[g][k]     (fold q=hh algebra)
//            k>=128: W_ih[g][k]                  (r columns)   (256 x 512)
__global__ void k_prep(const float* __restrict__ W_in,
                       const float* __restrict__ W_ih,
                       const float* __restrict__ W_hh,
                       float* __restrict__ Wt_in,
                       float* __restrict__ Wt2,
                       int* __restrict__ cnt) {
    int idx = blockIdx.x * 256 + threadIdx.x;
    if (idx < N_NODES) cnt[idx] = 0;
    if (idx < D_INP * D_HID) {
        int k = idx / D_HID, d = idx % D_HID;
        Wt_in[idx] = W_in[d * D_INP + k];
    }
    if (idx < 256 * 512) {
        int k = idx / 512, g = idx % 512;
        float v = W_ih[g * 256 + k];
        if (k < 128) v += W_hh[g * 128 + k];
        Wt2[idx] = v;
    }
}

// ---------------------------------------------------------------------------
// Single-pass edge bucketing + seg_ptr. No LDS -> full occupancy for the
// atomic/scatter latency (the R9 fat-kernel lesson).
__global__ void k_bucket(const int* __restrict__ src, const int* __restrict__ dst,
                         const int* __restrict__ batch,
                         int* __restrict__ cnt, int* __restrict__ esrc,
                         int* __restrict__ seg_ptr) {
    int e = blockIdx.x * 256 + threadIdx.x;
    if (e < N_EDGES) {
        int d = dst[e];
        int p = atomicAdd(&cnt[d], 1);
        if (p < CAP) esrc[d * CAP + p] = src[e];
    }
    if (e < N_NODES) {
        int n = e;
        int bc = batch[n];
        int bp = (n == 0) ? -1 : batch[n - 1];
        for (int b = bp + 1; b <= bc; b++) seg_ptr[b] = n;
        if (n == N_NODES - 1)
            for (int b = bc + 1; b <= N_B; b++) seg_ptr[b] = N_NODES;
    }
}

// ---------------------------------------------------------------------------
// Input layer: h = relu(x @ W_in^T + b_in); 64x64 tile, padded xs.
__global__ __launch_bounds__(256) void k_ingemm(const float* __restrict__ x,
                                                const float* __restrict__ Wt_in,
                                                const float* __restrict__ b_in,
                                                float* __restrict__ h) {
    __shared__ __align__(16) float xs[64 * XS_LD];   // 25.6 KB
    __shared__ __align__(16) float ws[96 * 64];      // 24 KB
    int n0 = blockIdx.x * 64;
    int d0 = blockIdx.y * 64;
    int tid = threadIdx.x;
    for (int j = tid; j < 64 * 96 / 4; j += 256) {
        int row = (j * 4) / 96, col = (j * 4) % 96;
        int node = n0 + row;
        float4 v = make_float4(0.f, 0.f, 0.f, 0.f);
        if (node < N_NODES) v = *(const float4*)&x[(size_t)node * 96 + col];
        *(float4*)&xs[row * XS_LD + col] = v;
    }
    for (int j = tid; j < 96 * 64 / 4; j += 256) {
        int k = (j * 4) / 64, dd = (j * 4) % 64;
        *(float4*)&ws[j * 4] = *(const float4*)&Wt_in[k * D_HID + d0 + dd];
    }
    __syncthreads();
    int tn = tid / 16;
    int td = tid % 16;
    float acc[4][4] = {};
    for (int k0 = 0; k0 < 96; k0 += 4) {
        float4 w0 = *(float4*)&ws[(k0 + 0) * 64 + td * 4];
        float4 w1 = *(float4*)&ws[(k0 + 1) * 64 + td * 4];
        float4 w2 = *(float4*)&ws[(k0 + 2) * 64 + td * 4];
        float4 w3 = *(float4*)&ws[(k0 + 3) * 64 + td * 4];
#pragma unroll
        for (int j = 0; j < 4; j++) {
            float4 xv = *(float4*)&xs[(tn * 4 + j) * XS_LD + k0];
            acc[j][0] += xv.x * w0.x + xv.y * w1.x + xv.z * w2.x + xv.w * w3.x;
            acc[j][1] += xv.x * w0.y + xv.y * w1.y + xv.z * w2.y + xv.w * w3.y;
            acc[j][2] += xv.x * w0.z + xv.y * w1.z + xv.z * w2.z + xv.w * w3.z;
            acc[j][3] += xv.x * w0.w + xv.y * w1.w + xv.z * w2.w + xv.w * w3.w;
        }
    }
    float4 bb = *(const float4*)&b_in[d0 + td * 4];
#pragma unroll
    for (int j = 0; j < 4; j++) {
        int node = n0 + tn * 4 + j;
        if (node < N_NODES) {
            float4 o;
            o.x = fmaxf(acc[j][0] + bb.x, 0.f);
            o.y = fmaxf(acc[j][1] + bb.y, 0.f);
            o.z = fmaxf(acc[j][2] + bb.z, 0.f);
            o.w = fmaxf(acc[j][3] + bb.w, 0.f);
            *(float4*)&h[(size_t)node * D_HID + d0 + td * 4] = o;
        }
    }
}

// ---------------------------------------------------------------------------
// MPNN step (unroll x4). Bucketed esrc: row n at esrc[n*CAP], length cnt[n].
__global__ __launch_bounds__(256) void k_mpnn(const float* __restrict__ hin,
                                              float* __restrict__ hout,
                                              const int* __restrict__ cnt,
                                              const int* __restrict__ esrc) {
    int g = threadIdx.x >> 5;
    int l = threadIdx.x & 31;
    int n = blockIdx.x * 8 + g;
    if (n >= N_NODES) return;
    int deg = cnt[n];
    int len = min(deg, CAP);
    const int* row = &esrc[n * CAP];
    float4 a0 = {0,0,0,0}, a1 = {0,0,0,0}, a2 = {0,0,0,0}, a3 = {0,0,0,0};
    int i = 0;
    for (; i + 4 <= len; i += 4) {
        int e0 = row[i + 0];
        int e1 = row[i + 1];
        int e2 = row[i + 2];
        int e3 = row[i + 3];
        float4 v0 = *(const float4*)&hin[(size_t)e0 * 128 + l * 4];
        float4 v1 = *(const float4*)&hin[(size_t)e1 * 128 + l * 4];
        float4 v2 = *(const float4*)&hin[(size_t)e2 * 128 + l * 4];
        float4 v3 = *(const float4*)&hin[(size_t)e3 * 128 + l * 4];
        a0.x += v0.x; a0.y += v0.y; a0.z += v0.z; a0.w += v0.w;
        a1.x += v1.x; a1.y += v1.y; a1.z += v1.z; a1.w += v1.w;
        a2.x += v2.x; a2.y += v2.y; a2.z += v2.z; a2.w += v2.w;
        a3.x += v3.x; a3.y += v3.y; a3.z += v3.z; a3.w += v3.w;
    }
    for (; i < len; i++) {
        int e0 = row[i];
        float4 v0 = *(const float4*)&hin[(size_t)e0 * 128 + l * 4];
        a0.x += v0.x; a0.y += v0.y; a0.z += v0.z; a0.w += v0.w;
    }
    a0.x += a1.x + a2.x + a3.x;
    a0.y += a1.y + a2.y + a3.y;
    a0.z += a1.z + a2.z + a3.z;
    a0.w += a1.w + a2.w + a3.w;
    float invd = 1.0f / (float)max(deg, 1);
    float4 hv = *(const float4*)&hin[(size_t)n * 128 + l * 4];
    float4 o;
    o.x = (hv.x + a0.x * invd) * 0.5f;
    o.y = (hv.y + a0.y * invd) * 0.5f;
    o.z = (hv.z + a0.z * invd) * 0.5f;
    o.w = (hv.w + a0.w * invd) * 0.5f;
    *(float4*)&hout[(size_t)n * 128 + l * 4] = o;
}

__device__ __forceinline__ float sigmoidf_(float v) { return 1.0f / (1.0f + expf(-v)); }

// ---------------------------------------------------------------------------
// Fused Set2Set: 512 threads/block, 2 graphs/block, 8 lane-groups/graph,
// attention unrolled x2 with independent online-softmax states.
__global__ __launch_bounds__(512) void k_s2s2(const float* __restrict__ Wt2,
                                              const float* __restrict__ b_ih,
                                              const float* __restrict__ b_hh,
                                              const float* __restrict__ h,
                                              const int* __restrict__ seg_ptr,
                                              const float* __restrict__ W_pred,
                                              const float* __restrict__ b_pred,
                                              float* __restrict__ out) {
    __shared__ __align__(16) float in_s[2 * 256];   // [row][ hh(128) | r(128) ]
    __shared__ __align__(16) float c_s[2 * 128];
    __shared__ __align__(16) float gates_s[2 * 512];
    __shared__ float smax_s[2][8];
    __shared__ float ssum_s[2][8];
    __shared__ __align__(16) float sr_s[2][8][128];

    int t = threadIdx.x;
    in_s[t] = 0.f;
    if (t < 256) c_s[t] = 0.f;

    int row = t >> 8;
    int loc = t & 255;
    int gq  = loc >> 5;
    int l   = t & 31;
    int b   = blockIdx.x * 2 + row;
    int s0 = seg_ptr[b], s1 = seg_ptr[b + 1];

    float bia = b_ih[t] + b_hh[t];

    for (int step = 0; step < 3; step++) {
        __syncthreads();
        float acc0 = 0.f, acc1 = 0.f;
#pragma unroll 8
        for (int k = 0; k < 256; k++) {
            float w = Wt2[k * 512 + t];
            acc0 += in_s[k] * w;
            acc1 += in_s[256 + k] * w;
        }
        gates_s[t] = acc0 + bia;
        gates_s[512 + t] = acc1 + bia;
        __syncthreads();
        if (t < 256) {
            int r2 = t >> 7, f = t & 127;
            float ig = gates_s[r2 * 512 + f];
            float fg = gates_s[r2 * 512 + 128 + f];
            float gg = gates_s[r2 * 512 + 256 + f];
            float og = gates_s[r2 * 512 + 384 + f];
            float c = sigmoidf_(fg) * c_s[r2 * 128 + f] + sigmoidf_(ig) * tanhf(gg);
            c_s[r2 * 128 + f] = c;
            in_s[r2 * 256 + f] = sigmoidf_(og) * tanhf(c);
        }
        __syncthreads();
        float4 q = *(float4*)&in_s[row * 256 + l * 4];
        float Ma = -INFINITY, sa = 0.f;
        float Mb = -INFINITY, sb = 0.f;
        float4 ra = make_float4(0.f, 0.f, 0.f, 0.f);
        float4 rb = make_float4(0.f, 0.f, 0.f, 0.f);
        for (int n = s0 + gq; n < s1; n += 16) {
            {
                float4 hv = *(const float4*)&h[(size_t)n * 128 + l * 4];
                float d = hv.x * q.x + hv.y * q.y + hv.z * q.z + hv.w * q.w;
                for (int m = 16; m >= 1; m >>= 1) d += __shfl_xor(d, m, 64);
                float nM = fmaxf(Ma, d);
                float sc = expf(Ma - nM);
                float a = expf(d - nM);
                sa = sa * sc + a;
                ra.x = ra.x * sc + a * hv.x;
                ra.y = ra.y * sc + a * hv.y;
                ra.z = ra.z * sc + a * hv.z;
                ra.w = ra.w * sc + a * hv.w;
                Ma = nM;
            }
            int n2 = n + 8;
            if (n2 < s1) {
                float4 hv = *(const float4*)&h[(size_t)n2 * 128 + l * 4];
                float d = hv.x * q.x + hv.y * q.y + hv.z * q.z + hv.w * q.w;
                for (int m = 16; m >= 1; m >>= 1) d += __shfl_xor(d, m, 64);
                float nM = fmaxf(Mb, d);
                float sc = expf(Mb - nM);
                float a = expf(d - nM);
                sb = sb * sc + a;
                rb.x = rb.x * sc + a * hv.x;
                rb.y = rb.y * sc + a * hv.y;
                rb.z = rb.z * sc + a * hv.z;
                rb.w = rb.w * sc + a * hv.w;
                Mb = nM;
            }
        }
        float M = fmaxf(Ma, Mb);
        float wa = (Ma > -INFINITY) ? expf(Ma - M) : 0.f;
        float wb = (Mb > -INFINITY) ? expf(Mb - M) : 0.f;
        float asum = sa * wa + sb * wb;
        float4 racc;
        racc.x = ra.x * wa + rb.x * wb;
        racc.y = ra.y * wa + rb.y * wb;
        racc.z = ra.z * wa + rb.z * wb;
        racc.w = ra.w * wa + rb.w * wb;
        if (l == 0) { smax_s[row][gq] = M; ssum_s[row][gq] = asum; }
        *(float4*)&sr_s[row][gq][l * 4] = racc;
        __syncthreads();
        if (gq == 0) {
            float Mx = -INFINITY;
#pragma unroll
            for (int i = 0; i < 8; i++) Mx = fmaxf(Mx, smax_s[row][i]);
            float4 o = make_float4(0.f, 0.f, 0.f, 0.f);
            if (Mx > -INFINITY) {
                float tot = 0.f;
                float4 osum = make_float4(0.f, 0.f, 0.f, 0.f);
#pragma unroll
                for (int i = 0; i < 8; i++) {
                    float wi = expf(smax_s[row][i] - Mx);
                    tot += ssum_s[row][i] * wi;
                    float4 ri = *(float4*)&sr_s[row][i][l * 4];
                    osum.x += ri.x * wi; osum.y += ri.y * wi;
                    osum.z += ri.z * wi; osum.w += ri.w * wi;
                }
                float inv = 1.0f / (tot + 1e-16f);
                o.x = osum.x * inv; o.y = osum.y * inv;
                o.z = osum.z * inv; o.w = osum.w * inv;
            }
            *(float4*)&in_s[row * 256 + 128 + l * 4] = o;
            if (step == 2) {
                float4 wq = *(const float4*)&W_pred[l * 4];
                float4 wr = *(const float4*)&W_pred[128 + l * 4];
                float d = q.x * wq.x + q.y * wq.y + q.z * wq.z + q.w * wq.w
                        + o.x * wr.x + o.y * wr.y + o.z * wr.z + o.w * wr.w;
                for (int m = 16; m >= 1; m >>= 1) d += __shfl_xor(d, m, 64);
                if (l == 0) out[b] = d + b_pred[0];
            }
        }
    }
}

// ---------------------------------------------------------------------------
extern "C" void kernel_launch(void* const* d_in, const int* in_sizes, int n_in,
                              void* d_out, int out_size, void* d_ws, size_t ws_size,
                              hipStream_t stream) {
    const float* x      = (const float*)d_in[0];
    const int*   edge   = (const int*)d_in[1];
    const int*   batch  = (const int*)d_in[2];
    const float* W_in   = (const float*)d_in[3];
    const float* b_in   = (const float*)d_in[4];
    const float* W_ih   = (const float*)d_in[5];
    const float* W_hh   = (const float*)d_in[6];
    const float* b_ih   = (const float*)d_in[7];
    const float* b_hh   = (const float*)d_in[8];
    const float* W_pred = (const float*)d_in[9];
    const float* b_pred = (const float*)d_in[10];
    float* out = (float*)d_out;

    const int* src = edge;
    const int* dst = edge + N_EDGES;

    float* f = (float*)d_ws;
    float* h0    = f;                     f += (size_t)N_NODES * D_HID;
    float* h1    = f;                     f += (size_t)N_NODES * D_HID;
    float* Wt_in = f;                     f += D_INP * D_HID;
    float* Wt2   = f;                     f += 256 * 512;
    int* ip = (int*)f;
    int* cnt     = ip;                    ip += N_NODES;
    int* seg_ptr = ip;                    ip += N_B + 1 + 3;   // keep alignment
    int* esrc    = ip;                    ip += (size_t)N_NODES * CAP;

    // ---- weight prep + cnt zero
    k_prep<<<768, 256, 0, stream>>>(W_in, W_ih, W_hh, Wt_in, Wt2, cnt);

    // ---- edge bucketing + seg_ptr (LDS-free, high occupancy)
    k_bucket<<<(N_EDGES + 255) / 256, 256, 0, stream>>>(src, dst, batch,
                                                        cnt, esrc, seg_ptr);

    // ---- input layer
    k_ingemm<<<dim3((N_NODES + 63) / 64, 2), 256, 0, stream>>>(x, Wt_in, b_in, h0);

    // ---- 4 MPNN steps (ping-pong, ends in h0)
    int mb = (N_NODES + 7) / 8;
    k_mpnn<<<mb, 256, 0, stream>>>(h0, h1, cnt, esrc);
    k_mpnn<<<mb, 256, 0, stream>>>(h1, h0, cnt, esrc);
    k_mpnn<<<mb, 256, 0, stream>>>(h0, h1, cnt, esrc);
    k_mpnn<<<mb, 256, 0, stream>>>(h1, h0, cnt, esrc);

    // ---- fused Set2Set + head
    k_s2s2<<<N_B / 2, 512, 0, stream>>>(Wt2, b_ih, b_hh, h0, seg_ptr,
                                        W_pred, b_pred, out);
}

// Round 11
// 361.295 us; speedup vs baseline: 2.6531x; 1.2281x over previous
//
#include <hip/hip_runtime.h>
#include <math.h>
#include <float.h>

#define N_NODES 50000
#define N_EDGES 800000
#define D_INP   96
#define D_HID   128
#define N_B     512
#define CAP     64            // bucket capacity; in-degree ~Poisson(16), P(>64)~1e-17
#define XS_LD   100           // padded leading dim: avoids 4-way LDS conflict

typedef __attribute__((ext_vector_type(4))) _Float16 half4;

// ---------------------------------------------------------------------------
// Weight prep + zero cnt.
__global__ void k_prep(const float* __restrict__ W_in,
                       const float* __restrict__ W_ih,
                       const float* __restrict__ W_hh,
                       float* __restrict__ Wt_in,
                       float* __restrict__ Wt2,
                       int* __restrict__ cnt) {
    int idx = blockIdx.x * 256 + threadIdx.x;
    if (idx < N_NODES) cnt[idx] = 0;
    if (idx < D_INP * D_HID) {
        int k = idx / D_HID, d = idx % D_HID;
        Wt_in[idx] = W_in[d * D_INP + k];
    }
    if (idx < 256 * 512) {
        int k = idx / 512, g = idx % 512;
        float v = W_ih[g * 256 + k];
        if (k < 128) v += W_hh[g * 128 + k];
        Wt2[idx] = v;
    }
}

// ---------------------------------------------------------------------------
// Single-pass edge bucketing + seg_ptr (LDS-free -> high occupancy).
__global__ void k_bucket(const int* __restrict__ src, const int* __restrict__ dst,
                         const int* __restrict__ batch,
                         int* __restrict__ cnt, int* __restrict__ esrc,
                         int* __restrict__ seg_ptr) {
    int e = blockIdx.x * 256 + threadIdx.x;
    if (e < N_EDGES) {
        int d = dst[e];
        int p = atomicAdd(&cnt[d], 1);
        if (p < CAP) esrc[d * CAP + p] = src[e];
    }
    if (e < N_NODES) {
        int n = e;
        int bc = batch[n];
        int bp = (n == 0) ? -1 : batch[n - 1];
        for (int b = bp + 1; b <= bc; b++) seg_ptr[b] = n;
        if (n == N_NODES - 1)
            for (int b = bc + 1; b <= N_B; b++) seg_ptr[b] = N_NODES;
    }
}

// ---------------------------------------------------------------------------
// Input layer: h = relu(x @ W_in^T + b_in); writes fp32 h and fp16 shadow.
__global__ __launch_bounds__(256) void k_ingemm(const float* __restrict__ x,
                                                const float* __restrict__ Wt_in,
                                                const float* __restrict__ b_in,
                                                float* __restrict__ h,
                                                _Float16* __restrict__ h16) {
    __shared__ __align__(16) float xs[64 * XS_LD];
    __shared__ __align__(16) float ws[96 * 64];
    int n0 = blockIdx.x * 64;
    int d0 = blockIdx.y * 64;
    int tid = threadIdx.x;
    for (int j = tid; j < 64 * 96 / 4; j += 256) {
        int row = (j * 4) / 96, col = (j * 4) % 96;
        int node = n0 + row;
        float4 v = make_float4(0.f, 0.f, 0.f, 0.f);
        if (node < N_NODES) v = *(const float4*)&x[(size_t)node * 96 + col];
        *(float4*)&xs[row * XS_LD + col] = v;
    }
    for (int j = tid; j < 96 * 64 / 4; j += 256) {
        int k = (j * 4) / 64, dd = (j * 4) % 64;
        *(float4*)&ws[j * 4] = *(const float4*)&Wt_in[k * D_HID + d0 + dd];
    }
    __syncthreads();
    int tn = tid / 16;
    int td = tid % 16;
    float acc[4][4] = {};
    for (int k0 = 0; k0 < 96; k0 += 4) {
        float4 w0 = *(float4*)&ws[(k0 + 0) * 64 + td * 4];
        float4 w1 = *(float4*)&ws[(k0 + 1) * 64 + td * 4];
        float4 w2 = *(float4*)&ws[(k0 + 2) * 64 + td * 4];
        float4 w3 = *(float4*)&ws[(k0 + 3) * 64 + td * 4];
#pragma unroll
        for (int j = 0; j < 4; j++) {
            float4 xv = *(float4*)&xs[(tn * 4 + j) * XS_LD + k0];
            acc[j][0] += xv.x * w0.x + xv.y * w1.x + xv.z * w2.x + xv.w * w3.x;
            acc[j][1] += xv.x * w0.y + xv.y * w1.y + xv.z * w2.y + xv.w * w3.y;
            acc[j][2] += xv.x * w0.z + xv.y * w1.z + xv.z * w2.z + xv.w * w3.z;
            acc[j][3] += xv.x * w0.w + xv.y * w1.w + xv.z * w2.w + xv.w * w3.w;
        }
    }
    float4 bb = *(const float4*)&b_in[d0 + td * 4];
#pragma unroll
    for (int j = 0; j < 4; j++) {
        int node = n0 + tn * 4 + j;
        if (node < N_NODES) {
            float4 o;
            o.x = fmaxf(acc[j][0] + bb.x, 0.f);
            o.y = fmaxf(acc[j][1] + bb.y, 0.f);
            o.z = fmaxf(acc[j][2] + bb.z, 0.f);
            o.w = fmaxf(acc[j][3] + bb.w, 0.f);
            *(float4*)&h[(size_t)node * D_HID + d0 + td * 4] = o;
            half4 s;
            s.x = (_Float16)o.x; s.y = (_Float16)o.y;
            s.z = (_Float16)o.z; s.w = (_Float16)o.w;
            *(half4*)&h16[(size_t)node * D_HID + d0 + td * 4] = s;
        }
    }
}

// ---------------------------------------------------------------------------
// MPNN step: neighbor gathers from the fp16 shadow (256 B/row, half traffic);
// self term + update in fp32. Writes fp32 h (+fp16 shadow unless last step).
template <bool WRITE16>
__global__ __launch_bounds__(256) void k_mpnn(const float* __restrict__ hin,
                                              const _Float16* __restrict__ hin16,
                                              float* __restrict__ hout,
                                              _Float16* __restrict__ hout16,
                                              const int* __restrict__ cnt,
                                              const int* __restrict__ esrc) {
    int g = threadIdx.x >> 5;
    int l = threadIdx.x & 31;
    int n = blockIdx.x * 8 + g;
    if (n >= N_NODES) return;
    int deg = cnt[n];
    int len = min(deg, CAP);
    const int* row = &esrc[n * CAP];
    float4 a0 = {0,0,0,0}, a1 = {0,0,0,0}, a2 = {0,0,0,0}, a3 = {0,0,0,0};
    int i = 0;
    for (; i + 4 <= len; i += 4) {
        int e0 = row[i + 0];
        int e1 = row[i + 1];
        int e2 = row[i + 2];
        int e3 = row[i + 3];
        half4 v0 = *(const half4*)&hin16[(size_t)e0 * 128 + l * 4];
        half4 v1 = *(const half4*)&hin16[(size_t)e1 * 128 + l * 4];
        half4 v2 = *(const half4*)&hin16[(size_t)e2 * 128 + l * 4];
        half4 v3 = *(const half4*)&hin16[(size_t)e3 * 128 + l * 4];
        a0.x += (float)v0.x; a0.y += (float)v0.y; a0.z += (float)v0.z; a0.w += (float)v0.w;
        a1.x += (float)v1.x; a1.y += (float)v1.y; a1.z += (float)v1.z; a1.w += (float)v1.w;
        a2.x += (float)v2.x; a2.y += (float)v2.y; a2.z += (float)v2.z; a2.w += (float)v2.w;
        a3.x += (float)v3.x; a3.y += (float)v3.y; a3.z += (float)v3.z; a3.w += (float)v3.w;
    }
    for (; i < len; i++) {
        int e0 = row[i];
        half4 v0 = *(const half4*)&hin16[(size_t)e0 * 128 + l * 4];
        a0.x += (float)v0.x; a0.y += (float)v0.y; a0.z += (float)v0.z; a0.w += (float)v0.w;
    }
    a0.x += a1.x + a2.x + a3.x;
    a0.y += a1.y + a2.y + a3.y;
    a0.z += a1.z + a2.z + a3.z;
    a0.w += a1.w + a2.w + a3.w;
    float invd = 1.0f / (float)max(deg, 1);
    float4 hv = *(const float4*)&hin[(size_t)n * 128 + l * 4];
    float4 o;
    o.x = (hv.x + a0.x * invd) * 0.5f;
    o.y = (hv.y + a0.y * invd) * 0.5f;
    o.z = (hv.z + a0.z * invd) * 0.5f;
    o.w = (hv.w + a0.w * invd) * 0.5f;
    *(float4*)&hout[(size_t)n * 128 + l * 4] = o;
    if (WRITE16) {
        half4 s;
        s.x = (_Float16)o.x; s.y = (_Float16)o.y;
        s.z = (_Float16)o.z; s.w = (_Float16)o.w;
        *(half4*)&hout16[(size_t)n * 128 + l * 4] = s;
    }
}

__device__ __forceinline__ float sigmoidf_(float v) { return 1.0f / (1.0f + expf(-v)); }

// ---------------------------------------------------------------------------
// Fused Set2Set: 512 threads/block, 2 graphs/block, 8 lane-groups/graph,
// attention unrolled x2 with independent online-softmax states.
__global__ __launch_bounds__(512) void k_s2s2(const float* __restrict__ Wt2,
                                              const float* __restrict__ b_ih,
                                              const float* __restrict__ b_hh,
                                              const float* __restrict__ h,
                                              const int* __restrict__ seg_ptr,
                                              const float* __restrict__ W_pred,
                                              const float* __restrict__ b_pred,
                                              float* __restrict__ out) {
    __shared__ __align__(16) float in_s[2 * 256];   // [row][ hh(128) | r(128) ]
    __shared__ __align__(16) float c_s[2 * 128];
    __shared__ __align__(16) float gates_s[2 * 512];
    __shared__ float smax_s[2][8];
    __shared__ float ssum_s[2][8];
    __shared__ __align__(16) float sr_s[2][8][128];

    int t = threadIdx.x;
    in_s[t] = 0.f;
    if (t < 256) c_s[t] = 0.f;

    int row = t >> 8;
    int loc = t & 255;
    int gq  = loc >> 5;
    int l   = t & 31;
    int b   = blockIdx.x * 2 + row;
    int s0 = seg_ptr[b], s1 = seg_ptr[b + 1];

    float bia = b_ih[t] + b_hh[t];

    for (int step = 0; step < 3; step++) {
        __syncthreads();
        float acc0 = 0.f, acc1 = 0.f;
#pragma unroll 8
        for (int k = 0; k < 256; k++) {
            float w = Wt2[k * 512 + t];
            acc0 += in_s[k] * w;
            acc1 += in_s[256 + k] * w;
        }
        gates_s[t] = acc0 + bia;
        gates_s[512 + t] = acc1 + bia;
        __syncthreads();
        if (t < 256) {
            int r2 = t >> 7, f = t & 127;
            float ig = gates_s[r2 * 512 + f];
            float fg = gates_s[r2 * 512 + 128 + f];
            float gg = gates_s[r2 * 512 + 256 + f];
            float og = gates_s[r2 * 512 + 384 + f];
            float c = sigmoidf_(fg) * c_s[r2 * 128 + f] + sigmoidf_(ig) * tanhf(gg);
            c_s[r2 * 128 + f] = c;
            in_s[r2 * 256 + f] = sigmoidf_(og) * tanhf(c);
        }
        __syncthreads();
        float4 q = *(float4*)&in_s[row * 256 + l * 4];
        float Ma = -INFINITY, sa = 0.f;
        float Mb = -INFINITY, sb = 0.f;
        float4 ra = make_float4(0.f, 0.f, 0.f, 0.f);
        float4 rb = make_float4(0.f, 0.f, 0.f, 0.f);
        for (int n = s0 + gq; n < s1; n += 16) {
            {
                float4 hv = *(const float4*)&h[(size_t)n * 128 + l * 4];
                float d = hv.x * q.x + hv.y * q.y + hv.z * q.z + hv.w * q.w;
                for (int m = 16; m >= 1; m >>= 1) d += __shfl_xor(d, m, 64);
                float nM = fmaxf(Ma, d);
                float sc = expf(Ma - nM);
                float a = expf(d - nM);
                sa = sa * sc + a;
                ra.x = ra.x * sc + a * hv.x;
                ra.y = ra.y * sc + a * hv.y;
                ra.z = ra.z * sc + a * hv.z;
                ra.w = ra.w * sc + a * hv.w;
                Ma = nM;
            }
            int n2 = n + 8;
            if (n2 < s1) {
                float4 hv = *(const float4*)&h[(size_t)n2 * 128 + l * 4];
                float d = hv.x * q.x + hv.y * q.y + hv.z * q.z + hv.w * q.w;
                for (int m = 16; m >= 1; m >>= 1) d += __shfl_xor(d, m, 64);
                float nM = fmaxf(Mb, d);
                float sc = expf(Mb - nM);
                float a = expf(d - nM);
                sb = sb * sc + a;
                rb.x = rb.x * sc + a * hv.x;
                rb.y = rb.y * sc + a * hv.y;
                rb.z = rb.z * sc + a * hv.z;
                rb.w = rb.w * sc + a * hv.w;
                Mb = nM;
            }
        }
        float M = fmaxf(Ma, Mb);
        float wa = (Ma > -INFINITY) ? expf(Ma - M) : 0.f;
        float wb = (Mb > -INFINITY) ? expf(Mb - M) : 0.f;
        float asum = sa * wa + sb * wb;
        float4 racc;
        racc.x = ra.x * wa + rb.x * wb;
        racc.y = ra.y * wa + rb.y * wb;
        racc.z = ra.z * wa + rb.z * wb;
        racc.w = ra.w * wa + rb.w * wb;
        if (l == 0) { smax_s[row][gq] = M; ssum_s[row][gq] = asum; }
        *(float4*)&sr_s[row][gq][l * 4] = racc;
        __syncthreads();
        if (gq == 0) {
            float Mx = -INFINITY;
#pragma unroll
            for (int i = 0; i < 8; i++) Mx = fmaxf(Mx, smax_s[row][i]);
            float4 o = make_float4(0.f, 0.f, 0.f, 0.f);
            if (Mx > -INFINITY) {
                float tot = 0.f;
                float4 osum = make_float4(0.f, 0.f, 0.f, 0.f);
#pragma unroll
                for (int i = 0; i < 8; i++) {
                    float wi = expf(smax_s[row][i] - Mx);
                    tot += ssum_s[row][i] * wi;
                    float4 ri = *(float4*)&sr_s[row][i][l * 4];
                    osum.x += ri.x * wi; osum.y += ri.y * wi;
                    osum.z += ri.z * wi; osum.w += ri.w * wi;
                }
                float inv = 1.0f / (tot + 1e-16f);
                o.x = osum.x * inv; o.y = osum.y * inv;
                o.z = osum.z * inv; o.w = osum.w * inv;
            }
            *(float4*)&in_s[row * 256 + 128 + l * 4] = o;
            if (step == 2) {
                float4 wq = *(const float4*)&W_pred[l * 4];
                float4 wr = *(const float4*)&W_pred[128 + l * 4];
                float d = q.x * wq.x + q.y * wq.y + q.z * wq.z + q.w * wq.w
                        + o.x * wr.x + o.y * wr.y + o.z * wr.z + o.w * wr.w;
                for (int m = 16; m >= 1; m >>= 1) d += __shfl_xor(d, m, 64);
                if (l == 0) out[b] = d + b_pred[0];
            }
        }
    }
}

// ---------------------------------------------------------------------------
extern "C" void kernel_launch(void* const* d_in, const int* in_sizes, int n_in,
                              void* d_out, int out_size, void* d_ws, size_t ws_size,
                              hipStream_t stream) {
    const float* x      = (const float*)d_in[0];
    const int*   edge   = (const int*)d_in[1];
    const int*   batch  = (const int*)d_in[2];
    const float* W_in   = (const float*)d_in[3];
    const float* b_in   = (const float*)d_in[4];
    const float* W_ih   = (const float*)d_in[5];
    const float* W_hh   = (const float*)d_in[6];
    const float* b_ih   = (const float*)d_in[7];
    const float* b_hh   = (const float*)d_in[8];
    const float* W_pred = (const float*)d_in[9];
    const float* b_pred = (const float*)d_in[10];
    float* out = (float*)d_out;

    const int* src = edge;
    const int* dst = edge + N_EDGES;

    float* f = (float*)d_ws;
    float* h0    = f;                     f += (size_t)N_NODES * D_HID;
    float* h1    = f;                     f += (size_t)N_NODES * D_HID;
    _Float16* g0 = (_Float16*)f;          f += (size_t)N_NODES * D_HID / 2;
    _Float16* g1 = (_Float16*)f;          f += (size_t)N_NODES * D_HID / 2;
    float* Wt_in = f;                     f += D_INP * D_HID;
    float* Wt2   = f;                     f += 256 * 512;
    int* ip = (int*)f;
    int* cnt     = ip;                    ip += N_NODES;
    int* seg_ptr = ip;                    ip += N_B + 1 + 3;   // keep alignment
    int* esrc    = ip;                    ip += (size_t)N_NODES * CAP;

    // ---- weight prep + cnt zero
    k_prep<<<768, 256, 0, stream>>>(W_in, W_ih, W_hh, Wt_in, Wt2, cnt);

    // ---- edge bucketing + seg_ptr
    k_bucket<<<(N_EDGES + 255) / 256, 256, 0, stream>>>(src, dst, batch,
                                                        cnt, esrc, seg_ptr);

    // ---- input layer (fp32 h + fp16 shadow)
    k_ingemm<<<dim3((N_NODES + 63) / 64, 2), 256, 0, stream>>>(x, Wt_in, b_in, h0, g0);

    // ---- 4 MPNN steps: gather fp16, self/update fp32; last step fp32-only out
    int mb = (N_NODES + 7) / 8;
    k_mpnn<true ><<<mb, 256, 0, stream>>>(h0, g0, h1, g1, cnt, esrc);
    k_mpnn<true ><<<mb, 256, 0, stream>>>(h1, g1, h0, g0, cnt, esrc);
    k_mpnn<true ><<<mb, 256, 0, stream>>>(h0, g0, h1, g1, cnt, esrc);
    k_mpnn<false><<<mb, 256, 0, stream>>>(h1, g1, h0, g0, cnt, esrc);

    // ---- fused Set2Set + head (reads fp32 h0)
    k_s2s2<<<N_B / 2, 512, 0, stream>>>(Wt2, b_ih, b_hh, h0, seg_ptr,
                                        W_pred, b_pred, out);
}

// Round 12
// 346.284 us; speedup vs baseline: 2.7682x; 1.0433x over previous
//
#include <hip/hip_runtime.h>
#include <math.h>
#include <float.h>

#define N_NODES 50000
#define N_EDGES 800000
#define D_INP   96
#define D_HID   128
#define N_B     512
#define CAP     64            // bucket capacity; in-degree ~Poisson(16), P(>64)~1e-17
#define XS_LD   100           // padded leading dim: avoids 4-way LDS conflict

typedef __attribute__((ext_vector_type(4))) _Float16 half4;

// ---------------------------------------------------------------------------
// Weight prep + zero cnt.
__global__ void k_prep(const float* __restrict__ W_in,
                       const float* __restrict__ W_ih,
                       const float* __restrict__ W_hh,
                       float* __restrict__ Wt_in,
                       float* __restrict__ Wt2,
                       int* __restrict__ cnt) {
    int idx = blockIdx.x * 256 + threadIdx.x;
    if (idx < N_NODES) cnt[idx] = 0;
    if (idx < D_INP * D_HID) {
        int k = idx / D_HID, d = idx % D_HID;
        Wt_in[idx] = W_in[d * D_INP + k];
    }
    if (idx < 256 * 512) {
        int k = idx / 512, g = idx % 512;
        float v = W_ih[g * 256 + k];
        if (k < 128) v += W_hh[g * 128 + k];
        Wt2[idx] = v;
    }
}

// ---------------------------------------------------------------------------
// Single-pass edge bucketing + seg_ptr (LDS-free -> high occupancy).
__global__ void k_bucket(const int* __restrict__ src, const int* __restrict__ dst,
                         const int* __restrict__ batch,
                         int* __restrict__ cnt, int* __restrict__ esrc,
                         int* __restrict__ seg_ptr) {
    int e = blockIdx.x * 256 + threadIdx.x;
    if (e < N_EDGES) {
        int d = dst[e];
        int p = atomicAdd(&cnt[d], 1);
        if (p < CAP) esrc[d * CAP + p] = src[e];
    }
    if (e < N_NODES) {
        int n = e;
        int bc = batch[n];
        int bp = (n == 0) ? -1 : batch[n - 1];
        for (int b = bp + 1; b <= bc; b++) seg_ptr[b] = n;
        if (n == N_NODES - 1)
            for (int b = bc + 1; b <= N_B; b++) seg_ptr[b] = N_NODES;
    }
}

// ---------------------------------------------------------------------------
// Input layer: h = relu(x @ W_in^T + b_in); writes fp32 h and fp16 shadow.
__global__ __launch_bounds__(256) void k_ingemm(const float* __restrict__ x,
                                                const float* __restrict__ Wt_in,
                                                const float* __restrict__ b_in,
                                                float* __restrict__ h,
                                                _Float16* __restrict__ h16) {
    __shared__ __align__(16) float xs[64 * XS_LD];
    __shared__ __align__(16) float ws[96 * 64];
    int n0 = blockIdx.x * 64;
    int d0 = blockIdx.y * 64;
    int tid = threadIdx.x;
    for (int j = tid; j < 64 * 96 / 4; j += 256) {
        int row = (j * 4) / 96, col = (j * 4) % 96;
        int node = n0 + row;
        float4 v = make_float4(0.f, 0.f, 0.f, 0.f);
        if (node < N_NODES) v = *(const float4*)&x[(size_t)node * 96 + col];
        *(float4*)&xs[row * XS_LD + col] = v;
    }
    for (int j = tid; j < 96 * 64 / 4; j += 256) {
        int k = (j * 4) / 64, dd = (j * 4) % 64;
        *(float4*)&ws[j * 4] = *(const float4*)&Wt_in[k * D_HID + d0 + dd];
    }
    __syncthreads();
    int tn = tid / 16;
    int td = tid % 16;
    float acc[4][4] = {};
    for (int k0 = 0; k0 < 96; k0 += 4) {
        float4 w0 = *(float4*)&ws[(k0 + 0) * 64 + td * 4];
        float4 w1 = *(float4*)&ws[(k0 + 1) * 64 + td * 4];
        float4 w2 = *(float4*)&ws[(k0 + 2) * 64 + td * 4];
        float4 w3 = *(float4*)&ws[(k0 + 3) * 64 + td * 4];
#pragma unroll
        for (int j = 0; j < 4; j++) {
            float4 xv = *(float4*)&xs[(tn * 4 + j) * XS_LD + k0];
            acc[j][0] += xv.x * w0.x + xv.y * w1.x + xv.z * w2.x + xv.w * w3.x;
            acc[j][1] += xv.x * w0.y + xv.y * w1.y + xv.z * w2.y + xv.w * w3.y;
            acc[j][2] += xv.x * w0.z + xv.y * w1.z + xv.z * w2.z + xv.w * w3.z;
            acc[j][3] += xv.x * w0.w + xv.y * w1.w + xv.z * w2.w + xv.w * w3.w;
        }
    }
    float4 bb = *(const float4*)&b_in[d0 + td * 4];
#pragma unroll
    for (int j = 0; j < 4; j++) {
        int node = n0 + tn * 4 + j;
        if (node < N_NODES) {
            float4 o;
            o.x = fmaxf(acc[j][0] + bb.x, 0.f);
            o.y = fmaxf(acc[j][1] + bb.y, 0.f);
            o.z = fmaxf(acc[j][2] + bb.z, 0.f);
            o.w = fmaxf(acc[j][3] + bb.w, 0.f);
            *(float4*)&h[(size_t)node * D_HID + d0 + td * 4] = o;
            half4 s;
            s.x = (_Float16)o.x; s.y = (_Float16)o.y;
            s.z = (_Float16)o.z; s.w = (_Float16)o.w;
            *(half4*)&h16[(size_t)node * D_HID + d0 + td * 4] = s;
        }
    }
}

// ---------------------------------------------------------------------------
// MPNN step: neighbor gathers from the fp16 shadow (256 B/row, half traffic);
// self term + update in fp32. Writes fp32 h (+fp16 shadow unless last step).
template <bool WRITE16>
__global__ __launch_bounds__(256) void k_mpnn(const float* __restrict__ hin,
                                              const _Float16* __restrict__ hin16,
                                              float* __restrict__ hout,
                                              _Float16* __restrict__ hout16,
                                              const int* __restrict__ cnt,
                                              const int* __restrict__ esrc) {
    int g = threadIdx.x >> 5;
    int l = threadIdx.x & 31;
    int n = blockIdx.x * 8 + g;
    if (n >= N_NODES) return;
    int deg = cnt[n];
    int len = min(deg, CAP);
    const int* row = &esrc[n * CAP];
    float4 a0 = {0,0,0,0}, a1 = {0,0,0,0}, a2 = {0,0,0,0}, a3 = {0,0,0,0};
    int i = 0;
    for (; i + 4 <= len; i += 4) {
        int e0 = row[i + 0];
        int e1 = row[i + 1];
        int e2 = row[i + 2];
        int e3 = row[i + 3];
        half4 v0 = *(const half4*)&hin16[(size_t)e0 * 128 + l * 4];
        half4 v1 = *(const half4*)&hin16[(size_t)e1 * 128 + l * 4];
        half4 v2 = *(const half4*)&hin16[(size_t)e2 * 128 + l * 4];
        half4 v3 = *(const half4*)&hin16[(size_t)e3 * 128 + l * 4];
        a0.x += (float)v0.x; a0.y += (float)v0.y; a0.z += (float)v0.z; a0.w += (float)v0.w;
        a1.x += (float)v1.x; a1.y += (float)v1.y; a1.z += (float)v1.z; a1.w += (float)v1.w;
        a2.x += (float)v2.x; a2.y += (float)v2.y; a2.z += (float)v2.z; a2.w += (float)v2.w;
        a3.x += (float)v3.x; a3.y += (float)v3.y; a3.z += (float)v3.z; a3.w += (float)v3.w;
    }
    for (; i < len; i++) {
        int e0 = row[i];
        half4 v0 = *(const half4*)&hin16[(size_t)e0 * 128 + l * 4];
        a0.x += (float)v0.x; a0.y += (float)v0.y; a0.z += (float)v0.z; a0.w += (float)v0.w;
    }
    a0.x += a1.x + a2.x + a3.x;
    a0.y += a1.y + a2.y + a3.y;
    a0.z += a1.z + a2.z + a3.z;
    a0.w += a1.w + a2.w + a3.w;
    float invd = 1.0f / (float)max(deg, 1);
    float4 hv = *(const float4*)&hin[(size_t)n * 128 + l * 4];
    float4 o;
    o.x = (hv.x + a0.x * invd) * 0.5f;
    o.y = (hv.y + a0.y * invd) * 0.5f;
    o.z = (hv.z + a0.z * invd) * 0.5f;
    o.w = (hv.w + a0.w * invd) * 0.5f;
    *(float4*)&hout[(size_t)n * 128 + l * 4] = o;
    if (WRITE16) {
        half4 s;
        s.x = (_Float16)o.x; s.y = (_Float16)o.y;
        s.z = (_Float16)o.z; s.w = (_Float16)o.w;
        *(half4*)&hout16[(size_t)n * 128 + l * 4] = s;
    }
}

__device__ __forceinline__ float sigmoidf_(float v) { return 1.0f / (1.0f + expf(-v)); }

// ---------------------------------------------------------------------------
// Fused Set2Set v3: 1024 threads/block (16 waves/CU), 2 graphs/block.
// GEMM split-K: thread t -> gate t&511, K-half t>>9, both rows; partials
// combined in LDS. Attention: 16 lane-groups/graph, x2-unrolled dual
// online-softmax states (dependent chain ~3).
__global__ __launch_bounds__(1024) void k_s2s2(const float* __restrict__ Wt2,
                                               const float* __restrict__ b_ih,
                                               const float* __restrict__ b_hh,
                                               const float* __restrict__ h,
                                               const int* __restrict__ seg_ptr,
                                               const float* __restrict__ W_pred,
                                               const float* __restrict__ b_pred,
                                               float* __restrict__ out) {
    __shared__ __align__(16) float in_s[2 * 256];     // [row][ hh(128) | r(128) ]
    __shared__ __align__(16) float c_s[2 * 128];
    __shared__ __align__(16) float gates_s[2 * 512];
    __shared__ __align__(16) float gpart_s[2][2][512]; // [khalf][row][gate]
    __shared__ float smax_s[2][16];
    __shared__ float ssum_s[2][16];
    __shared__ __align__(16) float sr_s[2][16][128];

    int t = threadIdx.x;
    if (t < 512) in_s[t] = 0.f;
    if (t < 256) c_s[t] = 0.f;

    int gate = t & 511;
    int kh   = t >> 9;              // K-half for the gates GEMM
    int row  = t >> 9;              // graph within block (attention mapping)
    int loc  = t & 511;
    int gq   = loc >> 5;            // 16 groups of 32 lanes per graph
    int l    = t & 31;
    int b    = blockIdx.x * 2 + row;
    int s0 = seg_ptr[b], s1 = seg_ptr[b + 1];

    for (int step = 0; step < 3; step++) {
        __syncthreads();
        // ---- gates GEMM, split-K: 128 iterations per thread, both rows
        {
            float acc0 = 0.f, acc1 = 0.f;
            int k0 = kh * 128;
#pragma unroll 8
            for (int k = k0; k < k0 + 128; k++) {
                float w = Wt2[k * 512 + gate];
                acc0 += in_s[k] * w;
                acc1 += in_s[256 + k] * w;
            }
            gpart_s[kh][0][gate] = acc0;
            gpart_s[kh][1][gate] = acc1;
        }
        __syncthreads();
        if (t < 512) {
            float bia = b_ih[t] + b_hh[t];
            gates_s[t]       = gpart_s[0][0][t] + gpart_s[1][0][t] + bia;
            gates_s[512 + t] = gpart_s[0][1][t] + gpart_s[1][1][t] + bia;
        }
        __syncthreads();
        // ---- LSTM: t < 256 -> (row r2, feature f)
        if (t < 256) {
            int r2 = t >> 7, ff = t & 127;
            float ig = gates_s[r2 * 512 + ff];
            float fg = gates_s[r2 * 512 + 128 + ff];
            float gg = gates_s[r2 * 512 + 256 + ff];
            float og = gates_s[r2 * 512 + 384 + ff];
            float c = sigmoidf_(fg) * c_s[r2 * 128 + ff] + sigmoidf_(ig) * tanhf(gg);
            c_s[r2 * 128 + ff] = c;
            in_s[r2 * 256 + ff] = sigmoidf_(og) * tanhf(c);   // hh (= q)
        }
        __syncthreads();
        // ---- attention: 16 groups/graph, 2 independent online states/group
        float4 q = *(float4*)&in_s[row * 256 + l * 4];
        float Ma = -INFINITY, sa = 0.f;
        float Mb = -INFINITY, sb = 0.f;
        float4 ra = make_float4(0.f, 0.f, 0.f, 0.f);
        float4 rb = make_float4(0.f, 0.f, 0.f, 0.f);
        for (int n = s0 + gq; n < s1; n += 32) {
            {
                float4 hv = *(const float4*)&h[(size_t)n * 128 + l * 4];
                float d = hv.x * q.x + hv.y * q.y + hv.z * q.z + hv.w * q.w;
                for (int m = 16; m >= 1; m >>= 1) d += __shfl_xor(d, m, 64);
                float nM = fmaxf(Ma, d);
                float sc = expf(Ma - nM);
                float a = expf(d - nM);
                sa = sa * sc + a;
                ra.x = ra.x * sc + a * hv.x;
                ra.y = ra.y * sc + a * hv.y;
                ra.z = ra.z * sc + a * hv.z;
                ra.w = ra.w * sc + a * hv.w;
                Ma = nM;
            }
            int n2 = n + 16;
            if (n2 < s1) {
                float4 hv = *(const float4*)&h[(size_t)n2 * 128 + l * 4];
                float d = hv.x * q.x + hv.y * q.y + hv.z * q.z + hv.w * q.w;
                for (int m = 16; m >= 1; m >>= 1) d += __shfl_xor(d, m, 64);
                float nM = fmaxf(Mb, d);
                float sc = expf(Mb - nM);
                float a = expf(d - nM);
                sb = sb * sc + a;
                rb.x = rb.x * sc + a * hv.x;
                rb.y = rb.y * sc + a * hv.y;
                rb.z = rb.z * sc + a * hv.z;
                rb.w = rb.w * sc + a * hv.w;
                Mb = nM;
            }
        }
        float M = fmaxf(Ma, Mb);
        float wa = (Ma > -INFINITY) ? expf(Ma - M) : 0.f;
        float wb = (Mb > -INFINITY) ? expf(Mb - M) : 0.f;
        float asum = sa * wa + sb * wb;
        float4 racc;
        racc.x = ra.x * wa + rb.x * wb;
        racc.y = ra.y * wa + rb.y * wb;
        racc.z = ra.z * wa + rb.z * wb;
        racc.w = ra.w * wa + rb.w * wb;
        if (l == 0) { smax_s[row][gq] = M; ssum_s[row][gq] = asum; }
        *(float4*)&sr_s[row][gq][l * 4] = racc;
        __syncthreads();
        if (gq == 0) {
            float Mx = -INFINITY;
#pragma unroll
            for (int i = 0; i < 16; i++) Mx = fmaxf(Mx, smax_s[row][i]);
            float4 o = make_float4(0.f, 0.f, 0.f, 0.f);
            if (Mx > -INFINITY) {
                float tot = 0.f;
                float4 osum = make_float4(0.f, 0.f, 0.f, 0.f);
#pragma unroll
                for (int i = 0; i < 16; i++) {
                    float wi = expf(smax_s[row][i] - Mx);   // -inf -> 0
                    tot += ssum_s[row][i] * wi;
                    float4 ri = *(float4*)&sr_s[row][i][l * 4];
                    osum.x += ri.x * wi; osum.y += ri.y * wi;
                    osum.z += ri.z * wi; osum.w += ri.w * wi;
                }
                float inv = 1.0f / (tot + 1e-16f);
                o.x = osum.x * inv; o.y = osum.y * inv;
                o.z = osum.z * inv; o.w = osum.w * inv;
            }
            *(float4*)&in_s[row * 256 + 128 + l * 4] = o;   // r for next step
            if (step == 2) {
                float4 wq = *(const float4*)&W_pred[l * 4];
                float4 wr = *(const float4*)&W_pred[128 + l * 4];
                float d = q.x * wq.x + q.y * wq.y + q.z * wq.z + q.w * wq.w
                        + o.x * wr.x + o.y * wr.y + o.z * wr.z + o.w * wr.w;
                for (int m = 16; m >= 1; m >>= 1) d += __shfl_xor(d, m, 64);
                if (l == 0) out[b] = d + b_pred[0];
            }
        }
    }
}

// ---------------------------------------------------------------------------
extern "C" void kernel_launch(void* const* d_in, const int* in_sizes, int n_in,
                              void* d_out, int out_size, void* d_ws, size_t ws_size,
                              hipStream_t stream) {
    const float* x      = (const float*)d_in[0];
    const int*   edge   = (const int*)d_in[1];
    const int*   batch  = (const int*)d_in[2];
    const float* W_in   = (const float*)d_in[3];
    const float* b_in   = (const float*)d_in[4];
    const float* W_ih   = (const float*)d_in[5];
    const float* W_hh   = (const float*)d_in[6];
    const float* b_ih   = (const float*)d_in[7];
    const float* b_hh   = (const float*)d_in[8];
    const float* W_pred = (const float*)d_in[9];
    const float* b_pred = (const float*)d_in[10];
    float* out = (float*)d_out;

    const int* src = edge;
    const int* dst = edge + N_EDGES;

    float* f = (float*)d_ws;
    float* h0    = f;                     f += (size_t)N_NODES * D_HID;
    float* h1    = f;                     f += (size_t)N_NODES * D_HID;
    _Float16* g0 = (_Float16*)f;          f += (size_t)N_NODES * D_HID / 2;
    _Float16* g1 = (_Float16*)f;          f += (size_t)N_NODES * D_HID / 2;
    float* Wt_in = f;                     f += D_INP * D_HID;
    float* Wt2   = f;                     f += 256 * 512;
    int* ip = (int*)f;
    int* cnt     = ip;                    ip += N_NODES;
    int* seg_ptr = ip;                    ip += N_B + 1 + 3;   // keep alignment
    int* esrc    = ip;                    ip += (size_t)N_NODES * CAP;

    // ---- weight prep + cnt zero
    k_prep<<<768, 256, 0, stream>>>(W_in, W_ih, W_hh, Wt_in, Wt2, cnt);

    // ---- edge bucketing + seg_ptr
    k_bucket<<<(N_EDGES + 255) / 256, 256, 0, stream>>>(src, dst, batch,
                                                        cnt, esrc, seg_ptr);

    // ---- input layer (fp32 h + fp16 shadow)
    k_ingemm<<<dim3((N_NODES + 63) / 64, 2), 256, 0, stream>>>(x, Wt_in, b_in, h0, g0);

    // ---- 4 MPNN steps: gather fp16, self/update fp32; last step fp32-only out
    int mb = (N_NODES + 7) / 8;
    k_mpnn<true ><<<mb, 256, 0, stream>>>(h0, g0, h1, g1, cnt, esrc);
    k_mpnn<true ><<<mb, 256, 0, stream>>>(h1, g1, h0, g0, cnt, esrc);
    k_mpnn<true ><<<mb, 256, 0, stream>>>(h0, g0, h1, g1, cnt, esrc);
    k_mpnn<false><<<mb, 256, 0, stream>>>(h1, g1, h0, g0, cnt, esrc);

    // ---- fused Set2Set + head (reads fp32 h0)
    k_s2s2<<<N_B / 2, 1024, 0, stream>>>(Wt2, b_ih, b_hh, h0, seg_ptr,
                                         W_pred, b_pred, out);
}